// Round 9
// baseline (3203.724 us; speedup 1.0000x reference)
//
#include <hip/hip_runtime.h>

// RecurrentEncoder: proj(16->512)+relu, 3-layer LSTM (H=512), out head (512->16).
// B=256, T=128. Round 9: r8's ring-buffer persistent kernel + XCD COLOCATION:
// grid 256, role = (l = bid&7 if <3 else exit, n = bid>>3) -> with round-robin
// bid%8->XCD dispatch, each layer's 32 WGs share ONE XCD, so own-h exchange is
// L2-local (one fetch, 31 L2 hits) instead of 8 XCD-separate L3/HBM fetches.
// Mapping wrong => placement random = r8 behavior; correctness unaffected
// (volatile write-through stores + fresh-address cached loads, r7/r8-validated).
// Also: MFMA-loop unroll 8->16 (2x loads in flight; VGPR headroom is free at
// 1 wave/SIMD).

typedef __attribute__((ext_vector_type(8)))  short bf16x8;
typedef __attribute__((ext_vector_type(16))) float f32x16;
typedef __attribute__((ext_vector_type(8)))  unsigned short us8;

#define B_  256
#define T_  128
#define FIN 16
#define H_  512
#define G4  2048
#define MF(A,B,C) __builtin_amdgcn_mfma_f32_32x32x16_bf16(A,B,C,0,0,0)

static __device__ __forceinline__ float bf2f(unsigned short u){
  return __uint_as_float(((unsigned)u) << 16);
}
static __device__ __forceinline__ unsigned short f2bf(float f){  // RNE
  unsigned u = __float_as_uint(f);
  u += 0x7fffu + ((u >> 16) & 1u);
  return (unsigned short)(u >> 16);
}
static __device__ __forceinline__ float sigm(float x){ return 1.f/(1.f + __expf(-x)); }
static __device__ __forceinline__ float tanh_(float x){ return 1.f - 2.f/(__expf(2.f*x) + 1.f); }

// Wave-autonomous slot wait: lane i polls slots[i&31]; done when ALL >= v.
// Bounded (hang-proof); empty asm = compiler fence so cached ring loads can't
// hoist above the wait.
static __device__ __forceinline__ void wave_wait(const int* slotbase, int v){
  int guard = 0;
  for (;;){
    int s = __hip_atomic_load((const int*)(slotbase + (threadIdx.x & 31)),
                              __ATOMIC_RELAXED, __HIP_MEMORY_SCOPE_AGENT);
    if (__all(s >= v) || guard++ > (1 << 17)) break;
    __builtin_amdgcn_s_sleep(2);
  }
  asm volatile("" ::: "memory");
}

// ================= prep kernels (verified rounds 1-8) =================

// lstm_w fp32 [3][1024][2048] -> bf16, 32x32x16 A-frag order:
// wf[l][Jb=64][s=64][lane=64][e=8]; j' = Jb*32+(lane&31) (j' = hcol*4+gate),
// k = s*16 + (lane>>5)*8 + e.
__global__ __launch_bounds__(256) void k_wconv(const float* __restrict__ w,
                                               unsigned short* __restrict__ wfo){
  long idx = (long)blockIdx.x*256 + threadIdx.x;   // 786432 = 3*64*64*64
  int lane = (int)(idx & 63);
  int s    = (int)((idx >> 6) & 63);
  int Jb   = (int)((idx >> 12) & 63);
  int l    = (int)(idx >> 18);
  int jp = Jb*32 + (lane & 31);
  int co = (jp & 3)*512 + (jp >> 2);       // orig col = gate*512 + hcol
  int k0 = s*16 + (lane >> 5)*8;
  us8 o;
  #pragma unroll
  for (int e = 0; e < 8; ++e)
    o[e] = f2bf(w[((long)(l*1024 + k0 + e))*2048 + co]);
  *(us8*)(wfo + idx*8) = o;
}

// xp = relu(x @ pw + pb) -> bf16, t-major: xpall[t][b][512]
__global__ __launch_bounds__(256) void k_xp(const float* __restrict__ x,
                                            const float* __restrict__ pw,
                                            const float* __restrict__ pb,
                                            unsigned short* __restrict__ xpall){
  __shared__ float sw[FIN*H_];
  __shared__ float sb[H_];
  int tid = threadIdx.x;
  for (int i = tid; i < FIN*H_; i += 256) sw[i] = pw[i];
  for (int i = tid; i < H_;     i += 256) sb[i] = pb[i];
  __syncthreads();
  int r0 = blockIdx.x * 64;
  int c0 = tid * 2;
  for (int rr = 0; rr < 64; ++rr){
    int r = r0 + rr;                       // flat b*T + t
    int b = r >> 7, t = r & 127;
    const float* xr = x + (long)r*FIN;
    float a0 = sb[c0], a1 = sb[c0+1];
    #pragma unroll
    for (int f = 0; f < FIN; ++f){
      float xv = xr[f];
      a0 += xv * sw[f*H_ + c0];
      a1 += xv * sw[f*H_ + c0 + 1];
    }
    ushort2 tmp;
    tmp.x = f2bf(fmaxf(a0, 0.f));
    tmp.y = f2bf(fmaxf(a1, 0.f));
    *(ushort2*)(xpall + ((long)t*256 + b)*512 + c0) = tmp;
  }
}

// y = ring[t][2] @ out_w + out_b ; grid 2048 (16 rows x 16 outs per WG)
__global__ __launch_bounds__(256) void k_out(const unsigned short* __restrict__ ring,
                                             const float* __restrict__ ow,
                                             const float* __restrict__ ob,
                                             float* __restrict__ dout){
  __shared__ float sw[H_*16];
  int tid = threadIdx.x;
  for (int i = tid; i < H_*16; i += 256) sw[i] = ow[i];
  __syncthreads();
  int r0 = blockIdx.x * 16;
  int rr = tid >> 4, o = tid & 15;
  int r = r0 + rr;                          // flat b*T + t
  int b = r >> 7, t = r & 127;
  const us8* hp = (const us8*)(ring + (((long)t*3 + 2)*256 + b)*512);
  float acc = ob[o];
  for (int k8 = 0; k8 < H_/8; ++k8){
    us8 v = hp[k8];
    #pragma unroll
    for (int e = 0; e < 8; ++e) acc += bf2f(v[e]) * sw[(k8*8 + e)*16 + o];
  }
  dout[(long)r*16 + o] = acc;
}

// ================= persistent RNN kernel =================

// cell writes h into LDS staging tile [256 rows][stride 18 shorts] (conflict-free)
#define CELLS(ACC, JB, RF) \
  { _Pragma("unroll") \
    for (int q = 0; q < 4; ++q){ \
      float iv = ACC[4*q+0], gv = ACC[4*q+1], fv = ACC[4*q+2], ov = ACC[4*q+3]; \
      float cp = cst[JB][RF][q]; \
      float cn = sigm(fv + 1.f)*cp + sigm(iv)*tanh_(gv); \
      float hn = sigm(ov)*tanh_(cn); \
      cst[JB][RF][q] = cn; \
      int row = row0 + RF*32 + l31; \
      int hcl = JB*8 + 2*q + l5; \
      hstage[row*18 + hcl] = f2bf(hn); \
    } }

// grid 256 (1 WG/CU via 137 KB LDS). Role: xcd = bid&7; workers xcd<3:
// l = xcd, n = bid>>3 (0..31). With round-robin bid%8->XCD dispatch, layer l's
// 32 WGs share XCD l -> own-h exchange is L2-local. Others exit immediately.
__global__ __launch_bounds__(256, 1) void k_rnn(
    const unsigned short* __restrict__ wf, const float* __restrict__ lb,
    unsigned short* ring, const unsigned short* __restrict__ xpall,
    int* slots)
{
  extern __shared__ unsigned char Wl[];    // 131072 + 9216
  const int bid = blockIdx.x;
  const int xcd = bid & 7;
  if (xcd >= 3) return;                    // 160 spare WGs exit
  const int l = xcd;
  const int n = bid >> 3;

  unsigned short* hstage = (unsigned short*)(Wl + 131072);
  const int tid = threadIdx.x;
  const int lane = tid & 63;
  const int wv   = tid >> 6;
  const int l5 = lane >> 5, l31 = lane & 31;
  const int row0 = wv * 64;

  // ---- preload W slice into LDS (once) ----
  {
    const us8* src = (const us8*)(wf + ((long)(l*64 + n*2))*4096*8);
    us8* dst = (us8*)Wl;
    for (int i = tid; i < 8192; i += 256) dst[i] = src[i];
  }
  // ---- bias acc-init (D frag: j'_local = (r&3)+8*(r>>2)+4*l5) ----
  f32x16 bias0, bias1;
  #pragma unroll
  for (int r = 0; r < 16; ++r){
    int hc0 = (n*2 + 0)*8 + 2*(r>>2) + l5;
    int hc1 = (n*2 + 1)*8 + 2*(r>>2) + l5;
    bias0[r] = lb[l*G4 + (r&3)*512 + hc0];
    bias1[r] = lb[l*G4 + (r&3)*512 + hc1];
  }
  float cst[2][2][4] = {};                 // register c-state
  __syncthreads();

  const int* sOwn  = slots + l*32;
  const int* sPrev = slots + (l-1)*32;
  int* mySlot = slots + l*32 + n;

  for (int t = 0; t < T_; ++t){
    f32x16 a00 = bias0, a01 = bias0, a10 = bias1, a11 = bias1;

    // ---- l==0: xp left half FIRST (no deps; own-layer wait hides under it) ----
    if (l == 0){
      const unsigned short* p0 = xpall + (long)t*256*512
                               + ((long)(row0 + l31))*512 + l5*8;
      const unsigned short* p1 = p0 + 32*512;
      #pragma unroll 16
      for (int s = 0; s < 32; ++s){
        bf16x8 w0 = *(const bf16x8*)(Wl + ((s*64 + lane) << 4));
        bf16x8 w1 = *(const bf16x8*)(Wl + ((4096 + s*64 + lane) << 4));
        bf16x8 b0 = *(const bf16x8*)(p0 + s*16);
        bf16x8 b1 = *(const bf16x8*)(p1 + s*16);
        a00 = MF(w0, b0, a00); a01 = MF(w0, b1, a01);
        a10 = MF(w1, b0, a10); a11 = MF(w1, b1, a11);
      }
    }
    // W1: all 32 WGs of own layer finished step t-1 (slot value >= t).
    if (t > 0) wave_wait(sOwn, t);

    // ---- right half: k in [512,1024) = own h[t-1] from ring (L2-local reads).
    if (t > 0){
      const unsigned short* p0 =
          ring + (((long)((t-1)*3 + l))*256 + row0 + l31)*512 + l5*8;
      const unsigned short* p1 = p0 + 32*512;
      #pragma unroll 16
      for (int s = 32; s < 64; ++s){
        bf16x8 w0 = *(const bf16x8*)(Wl + ((s*64 + lane) << 4));
        bf16x8 w1 = *(const bf16x8*)(Wl + ((4096 + s*64 + lane) << 4));
        bf16x8 b0 = *(const bf16x8*)(p0 + (s-32)*16);
        bf16x8 b1 = *(const bf16x8*)(p1 + (s-32)*16);
        a00 = MF(w0, b0, a00); a01 = MF(w0, b1, a01);
        a10 = MF(w1, b0, a10); a11 = MF(w1, b1, a11);
      }
    }
    // ---- l>0: wait layer below done step t, then relu(h[l-1][t]) left half ----
    if (l > 0){
      wave_wait(sPrev, t + 1);
      const unsigned short* p0 = ring + ((long)(t*3 + (l-1)))*256*512
                               + ((long)(row0 + l31))*512 + l5*8;
      const unsigned short* p1 = p0 + 32*512;
      #pragma unroll 16
      for (int s = 0; s < 32; ++s){
        bf16x8 w0 = *(const bf16x8*)(Wl + ((s*64 + lane) << 4));
        bf16x8 w1 = *(const bf16x8*)(Wl + ((4096 + s*64 + lane) << 4));
        bf16x8 b0 = *(const bf16x8*)(p0 + s*16);
        bf16x8 b1 = *(const bf16x8*)(p1 + s*16);
        #pragma unroll
        for (int e = 0; e < 8; ++e){        // relu on bf16: sign bit -> 0
          if (b0[e] < 0) b0[e] = 0;
          if (b1[e] < 0) b1[e] = 0;
        }
        a00 = MF(w0, b0, a00); a01 = MF(w0, b1, a01);
        a10 = MF(w1, b0, a10); a11 = MF(w1, b1, a11);
      }
    }
    // ---- LSTM cell in regs -> LDS h-stage ----
    CELLS(a00, 0, 0)
    CELLS(a01, 0, 1)
    CELLS(a10, 1, 0)
    CELLS(a11, 1, 1)
    __syncthreads();
    // ---- packed 16B write-through stores into ring (2 per thread) ----
    {
      unsigned short* hdst = ring + ((long)(t*3 + l))*256*512 + n*16;
      #pragma unroll
      for (int c = tid; c < 512; c += 256){
        int row = c >> 1, half = c & 1;
        us8 v = *(const us8*)(hstage + row*18 + half*8);
        *(volatile us8*)(hdst + (long)row*512 + half*8) = v;
      }
    }
    __syncthreads();   // per-wave vmcnt drained before barrier -> stores visible
    if (tid == 0)      // single posted store, no RMW
      __hip_atomic_store(mySlot, t + 1, __ATOMIC_RELAXED, __HIP_MEMORY_SCOPE_AGENT);
  }
}

// ================= round-0 fallback (compact) kernels =================

__global__ __launch_bounds__(256) void k_wconv0(const float* __restrict__ w,
                                                unsigned short* __restrict__ wf){
  long d8 = ((long)blockIdx.x*256 + threadIdx.x) * 8;
  int lane = (int)((d8 >> 3) & 63);
  int s    = (int)((d8 >> 9) & 31);
  int J    = (int)((d8 >> 14) & 127);
  int l    = (int)(d8 >> 21);
  int jj = lane & 15, khi = lane >> 4;
  int jp = J*16 + jj;
  int co = (jp & 3)*512 + (jp >> 2);
  int kbase = s*32 + khi*8;
  us8 o;
  #pragma unroll
  for (int e = 0; e < 8; ++e)
    o[e] = f2bf(w[((long)(l*1024 + kbase + e))*2048 + co]);
  *(us8*)(wf + d8) = o;
}

__global__ void k_iout(float* __restrict__ dout, const float* __restrict__ ob){
  int i = blockIdx.x*256 + threadIdx.x;
  if (i < B_*T_*16) dout[i] = ob[i & 15];
}

__global__ __launch_bounds__(256, 2) void k_stage0(
    const float* __restrict__ x, const float* __restrict__ pw, const float* __restrict__ pb,
    const unsigned short* __restrict__ wf, const float* __restrict__ lb,
    const float* __restrict__ ow, float* __restrict__ dout,
    float* __restrict__ cbuf, unsigned short* __restrict__ hb,
    int t, int l)
{
  __shared__ unsigned char Ab[32*2048];
  __shared__ float gsm[32*36];
  __shared__ float xrow[32*16];
  __shared__ float hcell[32*8];

  const int tid = threadIdx.x;
  const int bid = blockIdx.x;
  const int m = bid >> 6;
  const int n = ((bid & 7) << 3) | ((bid >> 3) & 7);
  const int pwr = t & 1, prd = pwr ^ 1;
  const int bg0 = m * 32;

  {
    const unsigned short* src = hb + (((long)prd*3 + l)*256 + bg0)*512;
    for (int i = 0; i < 8; ++i){
      int cid = tid + 256*i;
      int row = cid >> 6, cc = cid & 63;
      us8 v = *(const us8*)(src + (long)row*512 + cc*8);
      *(us8*)(Ab + ((row*2048 + 1024 + cc*16) ^ ((row & 7) << 4))) = v;
    }
  }
  if (l > 0){
    const unsigned short* src = hb + (((long)pwr*3 + (l-1))*256 + bg0)*512;
    for (int i = 0; i < 8; ++i){
      int cid = tid + 256*i;
      int row = cid >> 6, cc = cid & 63;
      us8 v = *(const us8*)(src + (long)row*512 + cc*8);
      #pragma unroll
      for (int e = 0; e < 8; ++e) v[e] = (v[e] & 0x8000u) ? (unsigned short)0 : v[e];
      *(us8*)(Ab + ((row*2048 + cc*16) ^ ((row & 7) << 4))) = v;
    }
  } else {
    {
      int e2 = tid*2;
      int br = e2 >> 4, f = e2 & 15;
      const float* xr = x + ((long)(bg0 + br)*T_ + t)*FIN;
      xrow[e2] = xr[f]; xrow[e2+1] = xr[f+1];
    }
    __syncthreads();
    for (int i = 0; i < 8; ++i){
      int cid = tid + 256*i;
      int row = cid >> 6, cc = cid & 63;
      int c0 = cc*8;
      us8 vv;
      #pragma unroll
      for (int j = 0; j < 8; ++j){
        float a = pb[c0 + j];
        #pragma unroll
        for (int f = 0; f < FIN; ++f) a += xrow[row*16 + f] * pw[f*H_ + c0 + j];
        vv[j] = f2bf(fmaxf(a, 0.f));
      }
      *(us8*)(Ab + ((row*2048 + cc*16) ^ ((row & 7) << 4))) = vv;
    }
  }
  __syncthreads();

  const int lane = tid & 63, wid = tid >> 6;
  const int wm = wid >> 1, wn = wid & 1;
  const int J = n*2 + wn;
  const int arow = wm*16 + (lane & 15);
  const unsigned abase = (unsigned)arow*2048 + ((lane >> 4) << 4);
  const unsigned axor = (unsigned)((arow & 7) << 4);
  const unsigned short* bp = wf + ((((long)l*128 + J)*32)*64 + lane)*8;

  typedef __attribute__((ext_vector_type(4))) float f32x4;
  f32x4 acc = {0.f, 0.f, 0.f, 0.f};
  #pragma unroll
  for (int s = 0; s < 32; ++s){
    bf16x8 af = *(const bf16x8*)(Ab + ((abase + s*64) ^ axor));
    bf16x8 bfr = *(const bf16x8*)(bp + (long)s*512);
    acc = __builtin_amdgcn_mfma_f32_16x16x32_bf16(af, bfr, acc, 0, 0, 0);
  }
  {
    int colb = wn*16 + (lane & 15);
    int rowb = wm*16 + ((lane >> 4) << 2);
    #pragma unroll
    for (int r = 0; r < 4; ++r) gsm[(rowb + r)*36 + colb] = acc[r];
  }
  __syncthreads();

  {
    int bl = tid >> 3, hc = tid & 7;
    float4 g4 = *(float4*)(&gsm[bl*36 + hc*4]);
    int hcol = n*8 + hc;
    int bgl = bg0 + bl;
    float iv = g4.x + lb[l*G4 + hcol];
    float gv = g4.y + lb[l*G4 + 512 + hcol];
    float fv = g4.z + lb[l*G4 + 1024 + hcol];
    float ov = g4.w + lb[l*G4 + 1536 + hcol];
    long coff = ((long)l*256 + bgl)*512 + hcol;
    float cp = cbuf[coff];
    float cn = sigm(fv + 1.f)*cp + sigm(iv)*tanh_(gv);
    float hn = sigm(ov)*tanh_(cn);
    cbuf[coff] = cn;
    hb[(((long)pwr*3 + l)*256 + bgl)*512 + hcol] = f2bf(hn);
    if (l == 2) hcell[bl*8 + hc] = hn;
  }
  if (l == 2){
    __syncthreads();
    #pragma unroll
    for (int q = 0; q < 2; ++q){
      int oid = tid + 256*q;
      int bl = oid >> 4, o = oid & 15;
      float a = 0.f;
      #pragma unroll
      for (int hc = 0; hc < 8; ++hc) a += hcell[bl*8 + hc] * ow[(n*8 + hc)*16 + o];
      atomicAdd(dout + ((long)(bg0 + bl)*T_ + t)*16 + o, a);
    }
  }
}

// ================= launch =================

extern "C" void kernel_launch(void* const* d_in, const int* in_sizes, int n_in,
                              void* d_out, int out_size, void* d_ws, size_t ws_size,
                              hipStream_t stream)
{
  const float* x  = (const float*)d_in[0];
  const float* pw = (const float*)d_in[1];
  const float* pb = (const float*)d_in[2];
  const float* lw = (const float*)d_in[3];
  const float* lb = (const float*)d_in[4];
  const float* ow = (const float*)d_in[5];
  const float* ob = (const float*)d_in[6];
  float* dout = (float*)d_out;

  char* ws = (char*)d_ws;
  size_t off = 0;
  auto carve = [&](size_t bytes){ char* p = ws + off; off += (bytes + 255) & ~(size_t)255; return p; };
  unsigned short* wf    = (unsigned short*)carve(3ull*64*4096*8*2);       // 12.58 MB
  unsigned short* ring  = (unsigned short*)carve(128ull*3*256*512*2);     // 100.66 MB
  unsigned short* xpall = (unsigned short*)carve((size_t)B_*T_*H_*2);     // 33.55 MB
  int*            slots = (int*)carve(512);                               // 3*32 ints
  size_t need_lux = off;                                                  // ~146.8 MB

  bool lux = (ws_size >= need_lux);
  if (lux)
    lux = (hipFuncSetAttribute((const void*)k_rnn,
                               hipFuncAttributeMaxDynamicSharedMemorySize,
                               140288) == hipSuccess);

  if (lux){
    hipMemsetAsync(slots, 0, 512, stream);
    k_wconv<<<3072, 256, 0, stream>>>(lw, wf);
    k_xp<<<512, 256, 0, stream>>>(x, pw, pb, xpall);
    k_rnn<<<256, 256, 140288, stream>>>(wf, lb, ring, xpall, slots);
    k_out<<<2048, 256, 0, stream>>>(ring, ow, ob, dout);
  } else {
    // round-0 compact fallback (proven, 2199 us)
    size_t o2 = 0;
    auto carve2 = [&](size_t bytes){ char* p = ws + o2; o2 += (bytes + 255) & ~(size_t)255; return p; };
    unsigned short* wf0   = (unsigned short*)carve2(3ull*1024*2048*2);
    float*          cbuf0 = (float*)carve2(3ull*256*512*4);
    unsigned short* hbuf0 = (unsigned short*)carve2(2ull*3*256*512*2);
    hipMemsetAsync(cbuf0, 0, 3ull*256*512*4 + 2ull*3*256*512*2, stream);
    k_wconv0<<<3072, 256, 0, stream>>>(lw, wf0);
    k_iout<<<2048, 256, 0, stream>>>(dout, ob);
    for (int t = 0; t < T_; ++t)
      for (int l = 0; l < 3; ++l)
        k_stage0<<<512, 256, 0, stream>>>(x, pw, pb, wf0, lb, ow, dout,
                                          cbuf0, hbuf0, t, l);
  }
}

// Round 10
// 1656.539 us; speedup vs baseline: 1.9340x; 1.9340x over previous
//
#include <hip/hip_runtime.h>

// RecurrentEncoder: proj(16->512)+relu, 3-layer LSTM (H=512), out head (512->16).
// B=256, T=128. Round 10: persistent kernel, 192 active WGs = (l:3)x(mg:2)x(n:32),
// XCD 2l+mg via bid&7 (r9-evidenced mapping, runtime-verified by XCC_ID rendezvous).
// Acts streamed via depth-7 global_load_lds DMA pipeline (m97-style sink) instead
// of VGPR loads (r9's 25us/step bottleneck). Own-layer h: plain cached stores ->
// shared intra-XCD L2 (only when rendezvous confirms colocation); cross-layer h:
// volatile write-through ring (r7-9 proven). W in LDS; c-state in regs; verified
// 32x32x16 swapped-operand MFMA.

typedef __attribute__((ext_vector_type(8)))  short bf16x8;
typedef __attribute__((ext_vector_type(16))) float f32x16;
typedef __attribute__((ext_vector_type(8)))  unsigned short us8;

#define B_  256
#define T_  128
#define FIN 16
#define H_  512
#define G4  2048
#define MF(A,B,C) __builtin_amdgcn_mfma_f32_32x32x16_bf16(A,B,C,0,0,0)

static __device__ __forceinline__ float bf2f(unsigned short u){
  return __uint_as_float(((unsigned)u) << 16);
}
static __device__ __forceinline__ unsigned short f2bf(float f){  // RNE
  unsigned u = __float_as_uint(f);
  u += 0x7fffu + ((u >> 16) & 1u);
  return (unsigned short)(u >> 16);
}
static __device__ __forceinline__ float sigm(float x){ return 1.f/(1.f + __expf(-x)); }
static __device__ __forceinline__ float tanh_(float x){ return 1.f - 2.f/(__expf(2.f*x) + 1.f); }

// Wave-autonomous slot wait (r8/r9 proven): lane i polls slots[i&31]; done when
// ALL >= v. Bounded; empty asm = fence so ring reads can't hoist above.
static __device__ __forceinline__ void wave_wait(const int* slotbase, int v){
  int guard = 0;
  for (;;){
    int s = __hip_atomic_load((const int*)(slotbase + (threadIdx.x & 31)),
                              __ATOMIC_RELAXED, __HIP_MEMORY_SCOPE_AGENT);
    if (__all(s >= v) || guard++ > (1 << 17)) break;
    __builtin_amdgcn_s_sleep(2);
  }
  asm volatile("" ::: "memory");
}

// ================= prep kernels (verified rounds 1-9) =================

// lstm_w fp32 [3][1024][2048] -> bf16, 32x32x16 A-frag order (r9 layout):
// wf[l][Jb=64][s=64][lane=64][e=8]; j' = Jb*32+(lane&31) (j' = hcol*4+gate).
__global__ __launch_bounds__(256) void k_wconv(const float* __restrict__ w,
                                               unsigned short* __restrict__ wfo){
  long idx = (long)blockIdx.x*256 + threadIdx.x;   // 786432
  int lane = (int)(idx & 63);
  int s    = (int)((idx >> 6) & 63);
  int Jb   = (int)((idx >> 12) & 63);
  int l    = (int)(idx >> 18);
  int jp = Jb*32 + (lane & 31);
  int co = (jp & 3)*512 + (jp >> 2);
  int k0 = s*16 + (lane >> 5)*8;
  us8 o;
  #pragma unroll
  for (int e = 0; e < 8; ++e)
    o[e] = f2bf(w[((long)(l*1024 + k0 + e))*2048 + co]);
  *(us8*)(wfo + idx*8) = o;
}

// xp = relu(x @ pw + pb) -> bf16, t-major: xpall[t][b][512]
__global__ __launch_bounds__(256) void k_xp(const float* __restrict__ x,
                                            const float* __restrict__ pw,
                                            const float* __restrict__ pb,
                                            unsigned short* __restrict__ xpall){
  __shared__ float sw[FIN*H_];
  __shared__ float sb[H_];
  int tid = threadIdx.x;
  for (int i = tid; i < FIN*H_; i += 256) sw[i] = pw[i];
  for (int i = tid; i < H_;     i += 256) sb[i] = pb[i];
  __syncthreads();
  int r0 = blockIdx.x * 64;
  int c0 = tid * 2;
  for (int rr = 0; rr < 64; ++rr){
    int r = r0 + rr;
    int b = r >> 7, t = r & 127;
    const float* xr = x + (long)r*FIN;
    float a0 = sb[c0], a1 = sb[c0+1];
    #pragma unroll
    for (int f = 0; f < FIN; ++f){
      float xv = xr[f];
      a0 += xv * sw[f*H_ + c0];
      a1 += xv * sw[f*H_ + c0 + 1];
    }
    ushort2 tmp;
    tmp.x = f2bf(fmaxf(a0, 0.f));
    tmp.y = f2bf(fmaxf(a1, 0.f));
    *(ushort2*)(xpall + ((long)t*256 + b)*512 + c0) = tmp;
  }
}

// y = cross[t][2] @ out_w + out_b ; grid 2048
__global__ __launch_bounds__(256) void k_out(const unsigned short* __restrict__ ring,
                                             const float* __restrict__ ow,
                                             const float* __restrict__ ob,
                                             float* __restrict__ dout){
  __shared__ float sw[H_*16];
  int tid = threadIdx.x;
  for (int i = tid; i < H_*16; i += 256) sw[i] = ow[i];
  __syncthreads();
  int r0 = blockIdx.x * 16;
  int rr = tid >> 4, o = tid & 15;
  int r = r0 + rr;
  int b = r >> 7, t = r & 127;
  const us8* hp = (const us8*)(ring + (((long)t*3 + 2)*256 + b)*512);
  float acc = ob[o];
  for (int k8 = 0; k8 < H_/8; ++k8){
    us8 v = hp[k8];
    #pragma unroll
    for (int e = 0; e < 8; ++e) acc += bf2f(v[e]) * sw[(k8*8 + e)*16 + o];
  }
  dout[(long)r*16 + o] = acc;
}

// ================= persistent RNN kernel =================

// DMA one 1-KB act tile (64 lanes x 16B, per-lane global addr, linear LDS dst).
#define DMA1(I) { \
  __builtin_amdgcn_global_load_lds( \
    (const __attribute__((address_space(1))) void*)(gsrc + (I)*16), \
    (__attribute__((address_space(3))) void*)(actb + (((I) & 7) << 10)), 16, 0, 0); }

// Wait oldest DMA landed + all prior ds_reads done; fence scheduling (rule 18).
#define WVL(N) { asm volatile("s_waitcnt vmcnt(" #N ") lgkmcnt(0)" ::: "memory"); \
                 __builtin_amdgcn_sched_barrier(0); }

#define CONS(I, RELU) { \
  bf16x8 w0 = *(const bf16x8*)(Wl + (((SB + (I))*64 + lane) << 4)); \
  bf16x8 w1 = *(const bf16x8*)(Wl + (65536 + (((SB + (I))*64 + lane) << 4))); \
  bf16x8 b  = *(const bf16x8*)(actb + (((I) & 7) << 10) + (lane << 4)); \
  if (RELU){ _Pragma("unroll") for (int e = 0; e < 8; ++e) if (b[e] < 0) b[e] = 0; } \
  a0 = MF(w0, b, a0); a1 = MF(w1, b, a1); }

#define STEPM(I, R) { WVL(6) DMA1((I)+7) CONS(I, R) }
#define GEMM_HALF(R) { \
  DMA1(0) DMA1(1) DMA1(2) DMA1(3) DMA1(4) DMA1(5) DMA1(6) \
  STEPM(0,R) STEPM(1,R) STEPM(2,R) STEPM(3,R) STEPM(4,R) \
  STEPM(5,R) STEPM(6,R) STEPM(7,R) STEPM(8,R) STEPM(9,R) \
  STEPM(10,R) STEPM(11,R) STEPM(12,R) STEPM(13,R) STEPM(14,R) \
  STEPM(15,R) STEPM(16,R) STEPM(17,R) STEPM(18,R) STEPM(19,R) \
  STEPM(20,R) STEPM(21,R) STEPM(22,R) STEPM(23,R) STEPM(24,R) \
  { WVL(6) CONS(25, R) } { WVL(5) CONS(26, R) } { WVL(4) CONS(27, R) } \
  { WVL(3) CONS(28, R) } { WVL(2) CONS(29, R) } { WVL(1) CONS(30, R) } \
  { WVL(0) CONS(31, R) } }

#define CELL1(A, JB) { _Pragma("unroll") \
  for (int q = 0; q < 4; ++q){ \
    float iv = A[4*q+0], gv = A[4*q+1], fv = A[4*q+2], ov = A[4*q+3]; \
    float cp = cs##JB[q]; \
    float cn = sigm(fv + 1.f)*cp + sigm(iv)*tanh_(gv); \
    float hn = sigm(ov)*tanh_(cn); \
    cs##JB[q] = cn; \
    hst[l31*16 + JB*8 + 2*q + l5] = f2bf(hn); } }

// grid 256, active 192: g = bid&7 (<6), l = g>>1, mg = g&1, n = bid>>3.
// block 256 = 4 waves, wave wv -> 32 rows (mg*128 + wv*32 ..). LDS = 160 KiB:
// W slice 128 KB + per-wave 8-slot act staging 4x8 KB (hstage aliases slot 0).
__global__ __launch_bounds__(256, 1) void k_rnn(
    const unsigned short* __restrict__ wf, const float* __restrict__ lb,
    unsigned short* ownring, unsigned short* crossring,
    const unsigned short* __restrict__ xpall,
    int* stepslots, int* xcdslots, int sepAvail)
{
  extern __shared__ unsigned char Wl[];     // 163840
  const int bid = blockIdx.x;
  const int g = bid & 7;
  if (g >= 6) return;
  const int l = g >> 1, mg = g & 1;
  const int n = bid >> 3;
  const int tid = threadIdx.x;
  const int lane = tid & 63;
  const int wv = tid >> 6;
  const int l5 = lane >> 5, l31 = lane & 31;
  const int mgrow = mg*128 + wv*32;
  unsigned char* actb = Wl + 131072 + (wv << 13);        // 8 KB per wave
  unsigned short* hst = (unsigned short*)actb;           // aliased post-GEMM

  // ---- preload W slice (Jb = 2n, 2n+1) into LDS ----
  {
    const us8* src = (const us8*)(wf + ((long)(l*64 + n*2))*4096*8);
    us8* dst = (us8*)Wl;
    for (int i = tid; i < 8192; i += 256) dst[i] = src[i];
  }
  // ---- bias acc-init (D frag: j'_local = (r&3)+8*(r>>2)+4*l5; r9-verified) ----
  f32x16 bias0, bias1;
  #pragma unroll
  for (int r = 0; r < 16; ++r){
    int hc0 = (n*2 + 0)*8 + 2*(r>>2) + l5;
    int hc1 = (n*2 + 1)*8 + 2*(r>>2) + l5;
    bias0[r] = lb[l*G4 + (r&3)*512 + hc0];
    bias1[r] = lb[l*G4 + (r&3)*512 + hc1];
  }
  float cs0[4] = {0.f,0.f,0.f,0.f}, cs1[4] = {0.f,0.f,0.f,0.f};
  __syncthreads();

  // ---- XCD rendezvous: own-ring normal stores are safe ONLY if all 32 WGs of
  //      this (l,mg) group share one XCD (intra-XCD L2 coherence). Verified at
  //      runtime -> correct under ANY dispatch mapping (G16). ----
  unsigned myxcd = 0;
  asm volatile("s_getreg_b32 %0, hwreg(HW_REG_XCC_ID)" : "=s"(myxcd));
  if (tid == 0)
    __hip_atomic_store(xcdslots + g*32 + n, 1 + (int)myxcd,
                       __ATOMIC_RELAXED, __HIP_MEMORY_SCOPE_AGENT);
  int uni;
  {
    int guard = 0, s = 0;
    for (;;){
      s = __hip_atomic_load((const int*)(xcdslots + g*32 + (lane & 31)),
                            __ATOMIC_RELAXED, __HIP_MEMORY_SCOPE_AGENT);
      if (__all(s >= 1) || guard++ > (1 << 17)) break;
      __builtin_amdgcn_s_sleep(2);
    }
    uni = __all(s == 1 + (int)myxcd);
    asm volatile("" ::: "memory");
  }
  const int ownSep = (sepAvail && uni) ? 1 : 0;
  const unsigned short* ownr = ownSep ? ownring : crossring;

  const int* sOwn  = stepslots + g*32;
  const int* sPrev = stepslots + (g - 2)*32;
  int* mySlot = stepslots + g*32 + n;

  for (int t = 0; t < T_; ++t){
    f32x16 a0 = bias0, a1 = bias1;

    if (l == 0){
      // xp left half first (no deps) -> own-wait hides under it
      {
        const unsigned short* gsrc = xpall + ((long)t*256 + mgrow + l31)*512 + l5*8;
        const int SB = 0;
        GEMM_HALF(0)
      }
      if (t > 0){
        wave_wait(sOwn, t);
        const unsigned short* gsrc =
            ownr + (((long)(t-1)*3 + l)*256 + mgrow + l31)*512 + l5*8;
        const int SB = 32;
        GEMM_HALF(0)
      }
    } else {
      if (t > 0){
        wave_wait(sOwn, t);
        const unsigned short* gsrc =
            ownr + (((long)(t-1)*3 + l)*256 + mgrow + l31)*512 + l5*8;
        const int SB = 32;
        GEMM_HALF(0)
      }
      wave_wait(sPrev, t + 1);
      {
        const unsigned short* gsrc =
            crossring + (((long)t*3 + (l-1))*256 + mgrow + l31)*512 + l5*8;
        const int SB = 0;
        GEMM_HALF(1)   // cross stores raw h; consumer applies relu
      }
    }

    // ---- LSTM cell (regs) -> per-wave LDS stage -> packed 16B ring stores ----
    CELL1(a0, 0)
    CELL1(a1, 1)
    asm volatile("s_waitcnt lgkmcnt(0)" ::: "memory");
    __builtin_amdgcn_sched_barrier(0);
    {
      us8 v = *(const us8*)(hst + (lane >> 1)*16 + (lane & 1)*8);
      long off = (((long)t*3 + l)*256 + mgrow + (lane >> 1))*512 + n*16 + (lane & 1)*8;
      if (ownSep) *(us8*)(ownring + off) = v;        // cached -> XCD L2 (dirty)
      *(volatile us8*)(crossring + off) = v;          // write-through -> L3
    }
    __syncthreads();   // drains all 4 waves' stores (vmcnt) before publish
    if (tid == 0)
      __hip_atomic_store(mySlot, t + 1, __ATOMIC_RELAXED, __HIP_MEMORY_SCOPE_AGENT);
  }
}

// ================= round-0 fallback (compact) kernels =================

__global__ __launch_bounds__(256) void k_wconv0(const float* __restrict__ w,
                                                unsigned short* __restrict__ wf){
  long d8 = ((long)blockIdx.x*256 + threadIdx.x) * 8;
  int lane = (int)((d8 >> 3) & 63);
  int s    = (int)((d8 >> 9) & 31);
  int J    = (int)((d8 >> 14) & 127);
  int l    = (int)(d8 >> 21);
  int jj = lane & 15, khi = lane >> 4;
  int jp = J*16 + jj;
  int co = (jp & 3)*512 + (jp >> 2);
  int kbase = s*32 + khi*8;
  us8 o;
  #pragma unroll
  for (int e = 0; e < 8; ++e)
    o[e] = f2bf(w[((long)(l*1024 + kbase + e))*2048 + co]);
  *(us8*)(wf + d8) = o;
}

__global__ void k_iout(float* __restrict__ dout, const float* __restrict__ ob){
  int i = blockIdx.x*256 + threadIdx.x;
  if (i < B_*T_*16) dout[i] = ob[i & 15];
}

__global__ __launch_bounds__(256, 2) void k_stage0(
    const float* __restrict__ x, const float* __restrict__ pw, const float* __restrict__ pb,
    const unsigned short* __restrict__ wf, const float* __restrict__ lb,
    const float* __restrict__ ow, float* __restrict__ dout,
    float* __restrict__ cbuf, unsigned short* __restrict__ hb,
    int t, int l)
{
  __shared__ unsigned char Ab[32*2048];
  __shared__ float gsm[32*36];
  __shared__ float xrow[32*16];
  __shared__ float hcell[32*8];

  const int tid = threadIdx.x;
  const int bid = blockIdx.x;
  const int m = bid >> 6;
  const int n = ((bid & 7) << 3) | ((bid >> 3) & 7);
  const int pwr = t & 1, prd = pwr ^ 1;
  const int bg0 = m * 32;

  {
    const unsigned short* src = hb + (((long)prd*3 + l)*256 + bg0)*512;
    for (int i = 0; i < 8; ++i){
      int cid = tid + 256*i;
      int row = cid >> 6, cc = cid & 63;
      us8 v = *(const us8*)(src + (long)row*512 + cc*8);
      *(us8*)(Ab + ((row*2048 + 1024 + cc*16) ^ ((row & 7) << 4))) = v;
    }
  }
  if (l > 0){
    const unsigned short* src = hb + (((long)pwr*3 + (l-1))*256 + bg0)*512;
    for (int i = 0; i < 8; ++i){
      int cid = tid + 256*i;
      int row = cid >> 6, cc = cid & 63;
      us8 v = *(const us8*)(src + (long)row*512 + cc*8);
      #pragma unroll
      for (int e = 0; e < 8; ++e) v[e] = (v[e] & 0x8000u) ? (unsigned short)0 : v[e];
      *(us8*)(Ab + ((row*2048 + cc*16) ^ ((row & 7) << 4))) = v;
    }
  } else {
    {
      int e2 = tid*2;
      int br = e2 >> 4, f = e2 & 15;
      const float* xr = x + ((long)(bg0 + br)*T_ + t)*FIN;
      xrow[e2] = xr[f]; xrow[e2+1] = xr[f+1];
    }
    __syncthreads();
    for (int i = 0; i < 8; ++i){
      int cid = tid + 256*i;
      int row = cid >> 6, cc = cid & 63;
      int c0 = cc*8;
      us8 vv;
      #pragma unroll
      for (int j = 0; j < 8; ++j){
        float a = pb[c0 + j];
        #pragma unroll
        for (int f = 0; f < FIN; ++f) a += xrow[row*16 + f] * pw[f*H_ + c0 + j];
        vv[j] = f2bf(fmaxf(a, 0.f));
      }
      *(us8*)(Ab + ((row*2048 + cc*16) ^ ((row & 7) << 4))) = vv;
    }
  }
  __syncthreads();

  const int lane = tid & 63, wid = tid >> 6;
  const int wm = wid >> 1, wn = wid & 1;
  const int J = n*2 + wn;
  const int arow = wm*16 + (lane & 15);
  const unsigned abase = (unsigned)arow*2048 + ((lane >> 4) << 4);
  const unsigned axor = (unsigned)((arow & 7) << 4);
  const unsigned short* bp = wf + ((((long)l*128 + J)*32)*64 + lane)*8;

  typedef __attribute__((ext_vector_type(4))) float f32x4;
  f32x4 acc = {0.f, 0.f, 0.f, 0.f};
  #pragma unroll
  for (int s = 0; s < 32; ++s){
    bf16x8 af = *(const bf16x8*)(Ab + ((abase + s*64) ^ axor));
    bf16x8 bfr = *(const bf16x8*)(bp + (long)s*512);
    acc = __builtin_amdgcn_mfma_f32_16x16x32_bf16(af, bfr, acc, 0, 0, 0);
  }
  {
    int colb = wn*16 + (lane & 15);
    int rowb = wm*16 + ((lane >> 4) << 2);
    #pragma unroll
    for (int r = 0; r < 4; ++r) gsm[(rowb + r)*36 + colb] = acc[r];
  }
  __syncthreads();

  {
    int bl = tid >> 3, hc = tid & 7;
    float4 g4 = *(float4*)(&gsm[bl*36 + hc*4]);
    int hcol = n*8 + hc;
    int bgl = bg0 + bl;
    float iv = g4.x + lb[l*G4 + hcol];
    float gv = g4.y + lb[l*G4 + 512 + hcol];
    float fv = g4.z + lb[l*G4 + 1024 + hcol];
    float ov = g4.w + lb[l*G4 + 1536 + hcol];
    long coff = ((long)l*256 + bgl)*512 + hcol;
    float cp = cbuf[coff];
    float cn = sigm(fv + 1.f)*cp + sigm(iv)*tanh_(gv);
    float hn = sigm(ov)*tanh_(cn);
    cbuf[coff] = cn;
    hb[(((long)pwr*3 + l)*256 + bgl)*512 + hcol] = f2bf(hn);
    if (l == 2) hcell[bl*8 + hc] = hn;
  }
  if (l == 2){
    __syncthreads();
    #pragma unroll
    for (int q = 0; q < 2; ++q){
      int oid = tid + 256*q;
      int bl = oid >> 4, o = oid & 15;
      float a = 0.f;
      #pragma unroll
      for (int hc = 0; hc < 8; ++hc) a += hcell[bl*8 + hc] * ow[(n*8 + hc)*16 + o];
      atomicAdd(dout + ((long)(bg0 + bl)*T_ + t)*16 + o, a);
    }
  }
}

// ================= launch =================

extern "C" void kernel_launch(void* const* d_in, const int* in_sizes, int n_in,
                              void* d_out, int out_size, void* d_ws, size_t ws_size,
                              hipStream_t stream)
{
  const float* x  = (const float*)d_in[0];
  const float* pw = (const float*)d_in[1];
  const float* pb = (const float*)d_in[2];
  const float* lw = (const float*)d_in[3];
  const float* lb = (const float*)d_in[4];
  const float* ow = (const float*)d_in[5];
  const float* ob = (const float*)d_in[6];
  float* dout = (float*)d_out;

  const size_t RING = 128ull*3*256*512*2;              // 100.66 MB
  char* ws = (char*)d_ws;
  size_t off = 0;
  auto carve = [&](size_t bytes){ char* p = ws + off; off += (bytes + 255) & ~(size_t)255; return p; };

  unsigned short* wf    = (unsigned short*)carve(3ull*64*4096*8*2);   // 12.58 MB
  unsigned short* cross = (unsigned short*)carve(RING);               // 100.66 MB
  unsigned short* xpall = (unsigned short*)carve((size_t)B_*T_*H_*2); // 33.55 MB
  int*            steps = (int*)carve(1024);
  int*            xcds  = (int*)carve(1024);
  size_t need_mid = off;                                              // ~146.9 MB
  unsigned short* own   = (unsigned short*)carve(RING);               // +100.66 MB
  size_t need_lux = off;                                              // ~247.5 MB

  int mode = (ws_size >= need_lux) ? 2 : (ws_size >= need_mid ? 1 : 0);
  if (mode){
    if (hipFuncSetAttribute((const void*)k_rnn,
                            hipFuncAttributeMaxDynamicSharedMemorySize,
                            163840) != hipSuccess)
      mode = 0;
  }

  if (mode){
    int sepAvail = (mode == 2) ? 1 : 0;
    unsigned short* ownp = sepAvail ? own : cross;
    hipMemsetAsync(steps, 0, 2048, stream);            // steps + xcds adjacent
    k_wconv<<<3072, 256, 0, stream>>>(lw, wf);
    k_xp<<<512, 256, 0, stream>>>(x, pw, pb, xpall);
    k_rnn<<<256, 256, 163840, stream>>>(wf, lb, ownp, cross, xpall,
                                        steps, xcds, sepAvail);
    k_out<<<2048, 256, 0, stream>>>(cross, ow, ob, dout);
  } else {
    // round-0 compact fallback (proven, 2199 us)
    size_t o2 = 0;
    auto carve2 = [&](size_t bytes){ char* p = ws + o2; o2 += (bytes + 255) & ~(size_t)255; return p; };
    unsigned short* wf0   = (unsigned short*)carve2(3ull*1024*2048*2);
    float*          cbuf0 = (float*)carve2(3ull*256*512*4);
    unsigned short* hbuf0 = (unsigned short*)carve2(2ull*3*256*512*2);
    hipMemsetAsync(cbuf0, 0, 3ull*256*512*4 + 2ull*3*256*512*2, stream);
    k_wconv0<<<3072, 256, 0, stream>>>(lw, wf0);
    k_iout<<<2048, 256, 0, stream>>>(dout, ob);
    for (int t = 0; t < T_; ++t)
      for (int l = 0; l < 3; ++l)
        k_stage0<<<512, 256, 0, stream>>>(x, pw, pb, wf0, lb, ow, dout,
                                          cbuf0, hbuf0, t, l);
  }
}

// Round 11
// 1585.251 us; speedup vs baseline: 2.0210x; 1.0450x over previous
//
#include <hip/hip_runtime.h>

// RecurrentEncoder: proj(16->512)+relu, 3-layer LSTM (H=512), out head (512->16).
// B=256, T=128. Round 11: r10 skeleton (persistent 192 WGs = (l:3)x(mg:2)x(n:32),
// XCD 2l+mg colocation w/ runtime XCC_ID rendezvous, DMA act staging, own-ring
// cached L2 exchange + cross-ring write-through, W in LDS, c in regs, verified
// 32x32x16 swapped-operand MFMA) with the GEMM DMA pipeline RESTRUCTURED:
// groups of 4 tiles, 2 groups in flight, vmcnt(4) once per group, NO per-iter
// lgkmcnt(0) (r10's serializer: 64x drained ds_read latency = ~8us/step); one
// lgkmcnt(0) per group guards LDS slot recycle. hstage stride 16->24 shorts.

typedef __attribute__((ext_vector_type(8)))  short bf16x8;
typedef __attribute__((ext_vector_type(16))) float f32x16;
typedef __attribute__((ext_vector_type(8)))  unsigned short us8;

#define B_  256
#define T_  128
#define FIN 16
#define H_  512
#define G4  2048
#define MF(A,B,C) __builtin_amdgcn_mfma_f32_32x32x16_bf16(A,B,C,0,0,0)

static __device__ __forceinline__ float bf2f(unsigned short u){
  return __uint_as_float(((unsigned)u) << 16);
}
static __device__ __forceinline__ unsigned short f2bf(float f){  // RNE
  unsigned u = __float_as_uint(f);
  u += 0x7fffu + ((u >> 16) & 1u);
  return (unsigned short)(u >> 16);
}
static __device__ __forceinline__ float sigm(float x){ return 1.f/(1.f + __expf(-x)); }
static __device__ __forceinline__ float tanh_(float x){ return 1.f - 2.f/(__expf(2.f*x) + 1.f); }

// Wave-autonomous slot wait (r8-r10 proven): lane i polls slots[i&31]; done when
// ALL >= v. Bounded; empty asm = fence so ring reads can't hoist above.
static __device__ __forceinline__ void wave_wait(const int* slotbase, int v){
  int guard = 0;
  for (;;){
    int s = __hip_atomic_load((const int*)(slotbase + (threadIdx.x & 31)),
                              __ATOMIC_RELAXED, __HIP_MEMORY_SCOPE_AGENT);
    if (__all(s >= v) || guard++ > (1 << 17)) break;
    __builtin_amdgcn_s_sleep(2);
  }
  asm volatile("" ::: "memory");
}

// ================= prep kernels (verified rounds 1-10) =================

// lstm_w fp32 [3][1024][2048] -> bf16, 32x32x16 A-frag order:
// wf[l][Jb=64][s=64][lane=64][e=8]; j' = Jb*32+(lane&31) (j' = hcol*4+gate).
__global__ __launch_bounds__(256) void k_wconv(const float* __restrict__ w,
                                               unsigned short* __restrict__ wfo){
  long idx = (long)blockIdx.x*256 + threadIdx.x;   // 786432
  int lane = (int)(idx & 63);
  int s    = (int)((idx >> 6) & 63);
  int Jb   = (int)((idx >> 12) & 63);
  int l    = (int)(idx >> 18);
  int jp = Jb*32 + (lane & 31);
  int co = (jp & 3)*512 + (jp >> 2);
  int k0 = s*16 + (lane >> 5)*8;
  us8 o;
  #pragma unroll
  for (int e = 0; e < 8; ++e)
    o[e] = f2bf(w[((long)(l*1024 + k0 + e))*2048 + co]);
  *(us8*)(wfo + idx*8) = o;
}

// xp = relu(x @ pw + pb) -> bf16, t-major: xpall[t][b][512]
__global__ __launch_bounds__(256) void k_xp(const float* __restrict__ x,
                                            const float* __restrict__ pw,
                                            const float* __restrict__ pb,
                                            unsigned short* __restrict__ xpall){
  __shared__ float sw[FIN*H_];
  __shared__ float sb[H_];
  int tid = threadIdx.x;
  for (int i = tid; i < FIN*H_; i += 256) sw[i] = pw[i];
  for (int i = tid; i < H_;     i += 256) sb[i] = pb[i];
  __syncthreads();
  int r0 = blockIdx.x * 64;
  int c0 = tid * 2;
  for (int rr = 0; rr < 64; ++rr){
    int r = r0 + rr;
    int b = r >> 7, t = r & 127;
    const float* xr = x + (long)r*FIN;
    float a0 = sb[c0], a1 = sb[c0+1];
    #pragma unroll
    for (int f = 0; f < FIN; ++f){
      float xv = xr[f];
      a0 += xv * sw[f*H_ + c0];
      a1 += xv * sw[f*H_ + c0 + 1];
    }
    ushort2 tmp;
    tmp.x = f2bf(fmaxf(a0, 0.f));
    tmp.y = f2bf(fmaxf(a1, 0.f));
    *(ushort2*)(xpall + ((long)t*256 + b)*512 + c0) = tmp;
  }
}

// y = cross[t][2] @ out_w + out_b ; grid 2048
__global__ __launch_bounds__(256) void k_out(const unsigned short* __restrict__ ring,
                                             const float* __restrict__ ow,
                                             const float* __restrict__ ob,
                                             float* __restrict__ dout){
  __shared__ float sw[H_*16];
  int tid = threadIdx.x;
  for (int i = tid; i < H_*16; i += 256) sw[i] = ow[i];
  __syncthreads();
  int r0 = blockIdx.x * 16;
  int rr = tid >> 4, o = tid & 15;
  int r = r0 + rr;
  int b = r >> 7, t = r & 127;
  const us8* hp = (const us8*)(ring + (((long)t*3 + 2)*256 + b)*512);
  float acc = ob[o];
  for (int k8 = 0; k8 < H_/8; ++k8){
    us8 v = hp[k8];
    #pragma unroll
    for (int e = 0; e < 8; ++e) acc += bf2f(v[e]) * sw[(k8*8 + e)*16 + o];
  }
  dout[(long)r*16 + o] = acc;
}

// ================= persistent RNN kernel =================

// DMA one 1-KB act tile (64 lanes x 16B, per-lane global addr, linear LDS dst).
#define DMA1(I) { \
  __builtin_amdgcn_global_load_lds( \
    (const __attribute__((address_space(1))) void*)(gsrc + (I)*16), \
    (__attribute__((address_space(3))) void*)(actb + (((I) & 7) << 10)), 16, 0, 0); }

#define ISSUE4(G) { DMA1((G)*4+0) DMA1((G)*4+1) DMA1((G)*4+2) DMA1((G)*4+3) }

// Counted vmcnt wait (oldest group landed); scheduling fenced (rule 18).
#define WVM(N) { asm volatile("s_waitcnt vmcnt(" #N ")" ::: "memory"); \
                 __builtin_amdgcn_sched_barrier(0); }
// Drain ds_reads before recycling their LDS slots for the next DMA group.
#define LGK0   { asm volatile("s_waitcnt lgkmcnt(0)" ::: "memory"); \
                 __builtin_amdgcn_sched_barrier(0); }

#define CONS(I, RELU) { \
  bf16x8 w0 = *(const bf16x8*)(Wl + (((SB + (I))*64 + lane) << 4)); \
  bf16x8 w1 = *(const bf16x8*)(Wl + (65536 + (((SB + (I))*64 + lane) << 4))); \
  bf16x8 b  = *(const bf16x8*)(actb + (((I) & 7) << 10) + (lane << 4)); \
  if (RELU){ _Pragma("unroll") for (int e = 0; e < 8; ++e) if (b[e] < 0) b[e] = 0; } \
  a0 = MF(w0, b, a0); a1 = MF(w1, b, a1); }

#define CONS4(G, R) { CONS((G)*4+0,R) CONS((G)*4+1,R) CONS((G)*4+2,R) CONS((G)*4+3,R) }

// 8 groups of 4 tiles, 2 groups in flight; compiler pipelines ds_reads inside
// each CONS4 with its own fine-grained lgkmcnt (no per-iter drain — r10's cost).
#define GEMM_HALF(R) { \
  ISSUE4(0) ISSUE4(1) \
  WVM(4) CONS4(0,R) LGK0 ISSUE4(2) \
  WVM(4) CONS4(1,R) LGK0 ISSUE4(3) \
  WVM(4) CONS4(2,R) LGK0 ISSUE4(4) \
  WVM(4) CONS4(3,R) LGK0 ISSUE4(5) \
  WVM(4) CONS4(4,R) LGK0 ISSUE4(6) \
  WVM(4) CONS4(5,R) LGK0 ISSUE4(7) \
  WVM(4) CONS4(6,R) \
  WVM(0) CONS4(7,R) }

// hstage: [32 rows][stride 24 shorts] -> 48B rows (16B-aligned us8 reads).
#define CELL1(A, JB) { _Pragma("unroll") \
  for (int q = 0; q < 4; ++q){ \
    float iv = A[4*q+0], gv = A[4*q+1], fv = A[4*q+2], ov = A[4*q+3]; \
    float cp = cs##JB[q]; \
    float cn = sigm(fv + 1.f)*cp + sigm(iv)*tanh_(gv); \
    float hn = sigm(ov)*tanh_(cn); \
    cs##JB[q] = cn; \
    hst[l31*24 + JB*8 + 2*q + l5] = f2bf(hn); } }

// grid 256, active 192: g = bid&7 (<6), l = g>>1, mg = g&1, n = bid>>3.
// block 256 = 4 waves, wave wv -> 32 rows. LDS = 160 KiB: W 128 KB + 4x8 KB act.
__global__ __launch_bounds__(256, 1) void k_rnn(
    const unsigned short* __restrict__ wf, const float* __restrict__ lb,
    unsigned short* ownring, unsigned short* crossring,
    const unsigned short* __restrict__ xpall,
    int* stepslots, int* xcdslots, int sepAvail)
{
  extern __shared__ unsigned char Wl[];     // 163840
  const int bid = blockIdx.x;
  const int g = bid & 7;
  if (g >= 6) return;
  const int l = g >> 1, mg = g & 1;
  const int n = bid >> 3;
  const int tid = threadIdx.x;
  const int lane = tid & 63;
  const int wv = tid >> 6;
  const int l5 = lane >> 5, l31 = lane & 31;
  const int mgrow = mg*128 + wv*32;
  unsigned char* actb = Wl + 131072 + (wv << 13);        // 8 KB per wave
  unsigned short* hst = (unsigned short*)actb;           // aliased post-GEMM

  // ---- preload W slice (Jb = 2n, 2n+1) into LDS ----
  {
    const us8* src = (const us8*)(wf + ((long)(l*64 + n*2))*4096*8);
    us8* dst = (us8*)Wl;
    for (int i = tid; i < 8192; i += 256) dst[i] = src[i];
  }
  // ---- bias acc-init (D frag: j'_local = (r&3)+8*(r>>2)+4*l5; verified) ----
  f32x16 bias0, bias1;
  #pragma unroll
  for (int r = 0; r < 16; ++r){
    int hc0 = (n*2 + 0)*8 + 2*(r>>2) + l5;
    int hc1 = (n*2 + 1)*8 + 2*(r>>2) + l5;
    bias0[r] = lb[l*G4 + (r&3)*512 + hc0];
    bias1[r] = lb[l*G4 + (r&3)*512 + hc1];
  }
  float cs0[4] = {0.f,0.f,0.f,0.f}, cs1[4] = {0.f,0.f,0.f,0.f};
  __syncthreads();

  // ---- XCD rendezvous (r10-proven): own-ring cached stores only if all 32 WGs
  //      of this (l,mg) group share one XCD; else volatile-only (G16-safe). ----
  unsigned myxcd = 0;
  asm volatile("s_getreg_b32 %0, hwreg(HW_REG_XCC_ID)" : "=s"(myxcd));
  if (tid == 0)
    __hip_atomic_store(xcdslots + g*32 + n, 1 + (int)myxcd,
                       __ATOMIC_RELAXED, __HIP_MEMORY_SCOPE_AGENT);
  int uni;
  {
    int guard = 0, s = 0;
    for (;;){
      s = __hip_atomic_load((const int*)(xcdslots + g*32 + (lane & 31)),
                            __ATOMIC_RELAXED, __HIP_MEMORY_SCOPE_AGENT);
      if (__all(s >= 1) || guard++ > (1 << 17)) break;
      __builtin_amdgcn_s_sleep(2);
    }
    uni = __all(s == 1 + (int)myxcd);
    asm volatile("" ::: "memory");
  }
  const int ownSep = (sepAvail && uni) ? 1 : 0;
  const unsigned short* ownr = ownSep ? ownring : crossring;

  const int* sOwn  = stepslots + g*32;
  const int* sPrev = stepslots + (g - 2)*32;
  int* mySlot = stepslots + g*32 + n;

  for (int t = 0; t < T_; ++t){
    f32x16 a0 = bias0, a1 = bias1;

    if (l == 0){
      // xp left half first (no deps) -> own-wait hides under it
      {
        const unsigned short* gsrc = xpall + ((long)t*256 + mgrow + l31)*512 + l5*8;
        const int SB = 0;
        GEMM_HALF(0)
      }
      if (t > 0){
        wave_wait(sOwn, t);
        const unsigned short* gsrc =
            ownr + (((long)(t-1)*3 + l)*256 + mgrow + l31)*512 + l5*8;
        const int SB = 32;
        GEMM_HALF(0)
      }
    } else {
      if (t > 0){
        wave_wait(sOwn, t);
        const unsigned short* gsrc =
            ownr + (((long)(t-1)*3 + l)*256 + mgrow + l31)*512 + l5*8;
        const int SB = 32;
        GEMM_HALF(0)
      }
      wave_wait(sPrev, t + 1);
      {
        const unsigned short* gsrc =
            crossring + (((long)t*3 + (l-1))*256 + mgrow + l31)*512 + l5*8;
        const int SB = 0;
        GEMM_HALF(1)   // cross stores raw h; consumer applies relu
      }
    }

    // ---- LSTM cell (regs) -> per-wave LDS stage -> packed 16B ring stores ----
    CELL1(a0, 0)
    CELL1(a1, 1)
    asm volatile("s_waitcnt lgkmcnt(0)" ::: "memory");
    __builtin_amdgcn_sched_barrier(0);
    {
      us8 v = *(const us8*)(hst + (lane >> 1)*24 + (lane & 1)*8);
      long off = (((long)t*3 + l)*256 + mgrow + (lane >> 1))*512 + n*16 + (lane & 1)*8;
      if (ownSep) *(us8*)(ownring + off) = v;         // cached -> XCD L2 (dirty)
      *(volatile us8*)(crossring + off) = v;           // write-through -> L3
    }
    __syncthreads();   // drains all 4 waves' stores before publish
    if (tid == 0)
      __hip_atomic_store(mySlot, t + 1, __ATOMIC_RELAXED, __HIP_MEMORY_SCOPE_AGENT);
  }
}

// ================= round-0 fallback (compact) kernels =================

__global__ __launch_bounds__(256) void k_wconv0(const float* __restrict__ w,
                                                unsigned short* __restrict__ wf){
  long d8 = ((long)blockIdx.x*256 + threadIdx.x) * 8;
  int lane = (int)((d8 >> 3) & 63);
  int s    = (int)((d8 >> 9) & 31);
  int J    = (int)((d8 >> 14) & 127);
  int l    = (int)(d8 >> 21);
  int jj = lane & 15, khi = lane >> 4;
  int jp = J*16 + jj;
  int co = (jp & 3)*512 + (jp >> 2);
  int kbase = s*32 + khi*8;
  us8 o;
  #pragma unroll
  for (int e = 0; e < 8; ++e)
    o[e] = f2bf(w[((long)(l*1024 + kbase + e))*2048 + co]);
  *(us8*)(wf + d8) = o;
}

__global__ void k_iout(float* __restrict__ dout, const float* __restrict__ ob){
  int i = blockIdx.x*256 + threadIdx.x;
  if (i < B_*T_*16) dout[i] = ob[i & 15];
}

__global__ __launch_bounds__(256, 2) void k_stage0(
    const float* __restrict__ x, const float* __restrict__ pw, const float* __restrict__ pb,
    const unsigned short* __restrict__ wf, const float* __restrict__ lb,
    const float* __restrict__ ow, float* __restrict__ dout,
    float* __restrict__ cbuf, unsigned short* __restrict__ hb,
    int t, int l)
{
  __shared__ unsigned char Ab[32*2048];
  __shared__ float gsm[32*36];
  __shared__ float xrow[32*16];
  __shared__ float hcell[32*8];

  const int tid = threadIdx.x;
  const int bid = blockIdx.x;
  const int m = bid >> 6;
  const int n = ((bid & 7) << 3) | ((bid >> 3) & 7);
  const int pwr = t & 1, prd = pwr ^ 1;
  const int bg0 = m * 32;

  {
    const unsigned short* src = hb + (((long)prd*3 + l)*256 + bg0)*512;
    for (int i = 0; i < 8; ++i){
      int cid = tid + 256*i;
      int row = cid >> 6, cc = cid & 63;
      us8 v = *(const us8*)(src + (long)row*512 + cc*8);
      *(us8*)(Ab + ((row*2048 + 1024 + cc*16) ^ ((row & 7) << 4))) = v;
    }
  }
  if (l > 0){
    const unsigned short* src = hb + (((long)pwr*3 + (l-1))*256 + bg0)*512;
    for (int i = 0; i < 8; ++i){
      int cid = tid + 256*i;
      int row = cid >> 6, cc = cid & 63;
      us8 v = *(const us8*)(src + (long)row*512 + cc*8);
      #pragma unroll
      for (int e = 0; e < 8; ++e) v[e] = (v[e] & 0x8000u) ? (unsigned short)0 : v[e];
      *(us8*)(Ab + ((row*2048 + cc*16) ^ ((row & 7) << 4))) = v;
    }
  } else {
    {
      int e2 = tid*2;
      int br = e2 >> 4, f = e2 & 15;
      const float* xr = x + ((long)(bg0 + br)*T_ + t)*FIN;
      xrow[e2] = xr[f]; xrow[e2+1] = xr[f+1];
    }
    __syncthreads();
    for (int i = 0; i < 8; ++i){
      int cid = tid + 256*i;
      int row = cid >> 6, cc = cid & 63;
      int c0 = cc*8;
      us8 vv;
      #pragma unroll
      for (int j = 0; j < 8; ++j){
        float a = pb[c0 + j];
        #pragma unroll
        for (int f = 0; f < FIN; ++f) a += xrow[row*16 + f] * pw[f*H_ + c0 + j];
        vv[j] = f2bf(fmaxf(a, 0.f));
      }
      *(us8*)(Ab + ((row*2048 + cc*16) ^ ((row & 7) << 4))) = vv;
    }
  }
  __syncthreads();

  const int lane = tid & 63, wid = tid >> 6;
  const int wm = wid >> 1, wn = wid & 1;
  const int J = n*2 + wn;
  const int arow = wm*16 + (lane & 15);
  const unsigned abase = (unsigned)arow*2048 + ((lane >> 4) << 4);
  const unsigned axor = (unsigned)((arow & 7) << 4);
  const unsigned short* bp = wf + ((((long)l*128 + J)*32)*64 + lane)*8;

  typedef __attribute__((ext_vector_type(4))) float f32x4;
  f32x4 acc = {0.f, 0.f, 0.f, 0.f};
  #pragma unroll
  for (int s = 0; s < 32; ++s){
    bf16x8 af = *(const bf16x8*)(Ab + ((abase + s*64) ^ axor));
    bf16x8 bfr = *(const bf16x8*)(bp + (long)s*512);
    acc = __builtin_amdgcn_mfma_f32_16x16x32_bf16(af, bfr, acc, 0, 0, 0);
  }
  {
    int colb = wn*16 + (lane & 15);
    int rowb = wm*16 + ((lane >> 4) << 2);
    #pragma unroll
    for (int r = 0; r < 4; ++r) gsm[(rowb + r)*36 + colb] = acc[r];
  }
  __syncthreads();

  {
    int bl = tid >> 3, hc = tid & 7;
    float4 g4 = *(float4*)(&gsm[bl*36 + hc*4]);
    int hcol = n*8 + hc;
    int bgl = bg0 + bl;
    float iv = g4.x + lb[l*G4 + hcol];
    float gv = g4.y + lb[l*G4 + 512 + hcol];
    float fv = g4.z + lb[l*G4 + 1024 + hcol];
    float ov = g4.w + lb[l*G4 + 1536 + hcol];
    long coff = ((long)l*256 + bgl)*512 + hcol;
    float cp = cbuf[coff];
    float cn = sigm(fv + 1.f)*cp + sigm(iv)*tanh_(gv);
    float hn = sigm(ov)*tanh_(cn);
    cbuf[coff] = cn;
    hb[(((long)pwr*3 + l)*256 + bgl)*512 + hcol] = f2bf(hn);
    if (l == 2) hcell[bl*8 + hc] = hn;
  }
  if (l == 2){
    __syncthreads();
    #pragma unroll
    for (int q = 0; q < 2; ++q){
      int oid = tid + 256*q;
      int bl = oid >> 4, o = oid & 15;
      float a = 0.f;
      #pragma unroll
      for (int hc = 0; hc < 8; ++hc) a += hcell[bl*8 + hc] * ow[(n*8 + hc)*16 + o];
      atomicAdd(dout + ((long)(bg0 + bl)*T_ + t)*16 + o, a);
    }
  }
}

// ================= launch =================

extern "C" void kernel_launch(void* const* d_in, const int* in_sizes, int n_in,
                              void* d_out, int out_size, void* d_ws, size_t ws_size,
                              hipStream_t stream)
{
  const float* x  = (const float*)d_in[0];
  const float* pw = (const float*)d_in[1];
  const float* pb = (const float*)d_in[2];
  const float* lw = (const float*)d_in[3];
  const float* lb = (const float*)d_in[4];
  const float* ow = (const float*)d_in[5];
  const float* ob = (const float*)d_in[6];
  float* dout = (float*)d_out;

  const size_t RING = 128ull*3*256*512*2;              // 100.66 MB
  char* ws = (char*)d_ws;
  size_t off = 0;
  auto carve = [&](size_t bytes){ char* p = ws + off; off += (bytes + 255) & ~(size_t)255; return p; };

  unsigned short* wf    = (unsigned short*)carve(3ull*64*4096*8*2);   // 12.58 MB
  unsigned short* cross = (unsigned short*)carve(RING);               // 100.66 MB
  unsigned short* xpall = (unsigned short*)carve((size_t)B_*T_*H_*2); // 33.55 MB
  int*            steps = (int*)carve(1024);
  int*            xcds  = (int*)carve(1024);
  size_t need_mid = off;                                              // ~146.9 MB
  unsigned short* own   = (unsigned short*)carve(RING);               // +100.66 MB
  size_t need_lux = off;                                              // ~247.5 MB

  int mode = (ws_size >= need_lux) ? 2 : (ws_size >= need_mid ? 1 : 0);
  if (mode){
    if (hipFuncSetAttribute((const void*)k_rnn,
                            hipFuncAttributeMaxDynamicSharedMemorySize,
                            163840) != hipSuccess)
      mode = 0;
  }

  if (mode){
    int sepAvail = (mode == 2) ? 1 : 0;
    unsigned short* ownp = sepAvail ? own : cross;
    hipMemsetAsync(steps, 0, 2048, stream);            // steps + xcds adjacent
    k_wconv<<<3072, 256, 0, stream>>>(lw, wf);
    k_xp<<<512, 256, 0, stream>>>(x, pw, pb, xpall);
    k_rnn<<<256, 256, 163840, stream>>>(wf, lb, ownp, cross, xpall,
                                        steps, xcds, sepAvail);
    k_out<<<2048, 256, 0, stream>>>(cross, ow, ob, dout);
  } else {
    // round-0 compact fallback (proven, 2199 us)
    size_t o2 = 0;
    auto carve2 = [&](size_t bytes){ char* p = ws + o2; o2 += (bytes + 255) & ~(size_t)255; return p; };
    unsigned short* wf0   = (unsigned short*)carve2(3ull*1024*2048*2);
    float*          cbuf0 = (float*)carve2(3ull*256*512*4);
    unsigned short* hbuf0 = (unsigned short*)carve2(2ull*3*256*512*2);
    hipMemsetAsync(cbuf0, 0, 3ull*256*512*4 + 2ull*3*256*512*2, stream);
    k_wconv0<<<3072, 256, 0, stream>>>(lw, wf0);
    k_iout<<<2048, 256, 0, stream>>>(dout, ob);
    for (int t = 0; t < T_; ++t)
      for (int l = 0; l < 3; ++l)
        k_stage0<<<512, 256, 0, stream>>>(x, pw, pb, wf0, lb, ow, dout,
                                          cbuf0, hbuf0, t, l);
  }
}

// Round 12
// 1335.033 us; speedup vs baseline: 2.3997x; 1.1874x over previous
//
#include <hip/hip_runtime.h>

// RecurrentEncoder: proj(16->512)+relu, 3-layer LSTM (H=512), out head (512->16).
// B=256, T=128. Round 12: r11 skeleton (persistent 192 WGs = (l:3)x(mg:2)x(n:32),
// XCD colocation + rendezvous, DMA staging, own-ring L2 / cross-ring L3 exchange,
// W in LDS, c in regs, verified 32x32x16 swapped MFMA) with act buffers RE-TILED:
// 1 KB lane-order tiles [(mg*4+rg)*32+s], element (row,kl) at (row+(kl>>3)*32)*8
// +(kl&7). Producer h-write = one coalesced 1 KB store (was 32-row scatter);
// each DMA = one contiguous 1 KB burst (was 32 scattered 32B segments — r11's
// transaction-rate wall). LDS contents identical; only addressing changed.

typedef __attribute__((ext_vector_type(8)))  short bf16x8;
typedef __attribute__((ext_vector_type(16))) float f32x16;
typedef __attribute__((ext_vector_type(8)))  unsigned short us8;

#define B_  256
#define T_  128
#define FIN 16
#define H_  512
#define G4  2048
#define SLAB 131072   // shorts per (t,l) slab = 256 rows x 512 cols
#define MF(A,B,C) __builtin_amdgcn_mfma_f32_32x32x16_bf16(A,B,C,0,0,0)

static __device__ __forceinline__ float bf2f(unsigned short u){
  return __uint_as_float(((unsigned)u) << 16);
}
static __device__ __forceinline__ unsigned short f2bf(float f){  // RNE
  unsigned u = __float_as_uint(f);
  u += 0x7fffu + ((u >> 16) & 1u);
  return (unsigned short)(u >> 16);
}
static __device__ __forceinline__ float sigm(float x){ return 1.f/(1.f + __expf(-x)); }
static __device__ __forceinline__ float tanh_(float x){ return 1.f - 2.f/(__expf(2.f*x) + 1.f); }

// Wave-autonomous slot wait (r8-r11 proven).
static __device__ __forceinline__ void wave_wait(const int* slotbase, int v){
  int guard = 0;
  for (;;){
    int s = __hip_atomic_load((const int*)(slotbase + (threadIdx.x & 31)),
                              __ATOMIC_RELAXED, __HIP_MEMORY_SCOPE_AGENT);
    if (__all(s >= v) || guard++ > (1 << 17)) break;
    __builtin_amdgcn_s_sleep(2);
  }
  asm volatile("" ::: "memory");
}

// ================= prep kernels =================

// lstm_w fp32 [3][1024][2048] -> bf16, 32x32x16 A-frag order (verified r1-r11).
__global__ __launch_bounds__(256) void k_wconv(const float* __restrict__ w,
                                               unsigned short* __restrict__ wfo){
  long idx = (long)blockIdx.x*256 + threadIdx.x;   // 786432
  int lane = (int)(idx & 63);
  int s    = (int)((idx >> 6) & 63);
  int Jb   = (int)((idx >> 12) & 63);
  int l    = (int)(idx >> 18);
  int jp = Jb*32 + (lane & 31);
  int co = (jp & 3)*512 + (jp >> 2);
  int k0 = s*16 + (lane >> 5)*8;
  us8 o;
  #pragma unroll
  for (int e = 0; e < 8; ++e)
    o[e] = f2bf(w[((long)(l*1024 + k0 + e))*2048 + co]);
  *(us8*)(wfo + idx*8) = o;
}

// xp = relu(x @ pw + pb) -> bf16 in TILED layout: slab t, tile (mg*4+rg)*32+s,
// element (row,kl) at (row + (kl>>3)*32)*8 + (kl&7).
__global__ __launch_bounds__(256) void k_xp(const float* __restrict__ x,
                                            const float* __restrict__ pw,
                                            const float* __restrict__ pb,
                                            unsigned short* __restrict__ xpt){
  __shared__ float sw[FIN*H_];
  __shared__ float sb[H_];
  int tid = threadIdx.x;
  for (int i = tid; i < FIN*H_; i += 256) sw[i] = pw[i];
  for (int i = tid; i < H_;     i += 256) sb[i] = pb[i];
  __syncthreads();
  int r0 = blockIdx.x * 64;
  int c0 = tid * 2;
  int s  = c0 >> 4, kl = c0 & 15;
  for (int rr = 0; rr < 64; ++rr){
    int r = r0 + rr;                       // flat b*T + t
    int b = r >> 7, t = r & 127;
    const float* xr = x + (long)r*FIN;
    float a0 = sb[c0], a1 = sb[c0+1];
    #pragma unroll
    for (int f = 0; f < FIN; ++f){
      float xv = xr[f];
      a0 += xv * sw[f*H_ + c0];
      a1 += xv * sw[f*H_ + c0 + 1];
    }
    ushort2 tmp;
    tmp.x = f2bf(fmaxf(a0, 0.f));
    tmp.y = f2bf(fmaxf(a1, 0.f));
    long off = (long)t*SLAB
             + ((((b>>7)*4 + ((b>>5)&3))*32 + s) << 9)
             + ((b&31) + ((kl>>3)<<5))*8 + (kl&7);
    *(ushort2*)(xpt + off) = tmp;
  }
}

// y = h2(tiled slab t,l=2) @ out_w + out_b ; grid 2048
__global__ __launch_bounds__(256) void k_out(const unsigned short* __restrict__ ring,
                                             const float* __restrict__ ow,
                                             const float* __restrict__ ob,
                                             float* __restrict__ dout){
  __shared__ float sw[H_*16];
  int tid = threadIdx.x;
  for (int i = tid; i < H_*16; i += 256) sw[i] = ow[i];
  __syncthreads();
  int r0 = blockIdx.x * 16;
  int rr = tid >> 4, o = tid & 15;
  int r = r0 + rr;                          // flat b*T + t
  int b = r >> 7, t = r & 127;
  long tb = ((long)t*3 + 2)*SLAB + (((b>>7)*4 + ((b>>5)&3)) << 14);  // *32*512
  float acc = ob[o];
  for (int k8 = 0; k8 < 64; ++k8){
    long off = tb + ((long)(k8 >> 1) << 9) + ((b&31) + ((k8&1)<<5))*8;
    us8 v = *(const us8*)(ring + off);
    #pragma unroll
    for (int e = 0; e < 8; ++e) acc += bf2f(v[e]) * sw[(k8*8 + e)*16 + o];
  }
  dout[(long)r*16 + o] = acc;
}

// ================= persistent RNN kernel =================

// DMA one CONTIGUOUS 1-KB tile (64 lanes x 16B sequential -> 16 full lines).
#define DMA1(I) { \
  __builtin_amdgcn_global_load_lds( \
    (const __attribute__((address_space(1))) void*)(gsrc + (I)*512), \
    (__attribute__((address_space(3))) void*)(actb + (((I) & 7) << 10)), 16, 0, 0); }

#define ISSUE4(G) { DMA1((G)*4+0) DMA1((G)*4+1) DMA1((G)*4+2) DMA1((G)*4+3) }

#define WVM(N) { asm volatile("s_waitcnt vmcnt(" #N ")" ::: "memory"); \
                 __builtin_amdgcn_sched_barrier(0); }
#define LGK0   { asm volatile("s_waitcnt lgkmcnt(0)" ::: "memory"); \
                 __builtin_amdgcn_sched_barrier(0); }

#define CONS(I, RELU) { \
  bf16x8 w0 = *(const bf16x8*)(Wl + (((SB + (I))*64 + lane) << 4)); \
  bf16x8 w1 = *(const bf16x8*)(Wl + (65536 + (((SB + (I))*64 + lane) << 4))); \
  bf16x8 b  = *(const bf16x8*)(actb + (((I) & 7) << 10) + (lane << 4)); \
  if (RELU){ _Pragma("unroll") for (int e = 0; e < 8; ++e) if (b[e] < 0) b[e] = 0; } \
  a0 = MF(w0, b, a0); a1 = MF(w1, b, a1); }

#define CONS4(G, R) { CONS((G)*4+0,R) CONS((G)*4+1,R) CONS((G)*4+2,R) CONS((G)*4+3,R) }

#define GEMM_HALF(R) { \
  ISSUE4(0) ISSUE4(1) \
  WVM(4) CONS4(0,R) LGK0 ISSUE4(2) \
  WVM(4) CONS4(1,R) LGK0 ISSUE4(3) \
  WVM(4) CONS4(2,R) LGK0 ISSUE4(4) \
  WVM(4) CONS4(3,R) LGK0 ISSUE4(5) \
  WVM(4) CONS4(4,R) LGK0 ISSUE4(6) \
  WVM(4) CONS4(5,R) LGK0 ISSUE4(7) \
  WVM(4) CONS4(6,R) \
  WVM(0) CONS4(7,R) }

// hstage: [32 rows][stride 24 shorts].
#define CELL1(A, JB) { _Pragma("unroll") \
  for (int q = 0; q < 4; ++q){ \
    float iv = A[4*q+0], gv = A[4*q+1], fv = A[4*q+2], ov = A[4*q+3]; \
    float cp = cs##JB[q]; \
    float cn = sigm(fv + 1.f)*cp + sigm(iv)*tanh_(gv); \
    float hn = sigm(ov)*tanh_(cn); \
    cs##JB[q] = cn; \
    hst[l31*24 + JB*8 + 2*q + l5] = f2bf(hn); } }

// grid 256, active 192: g = bid&7 (<6), l = g>>1, mg = g&1, n = bid>>3.
// block 256 = 4 waves, wave wv -> 32 rows. LDS = 160 KiB: W 128 KB + 4x8 KB act.
__global__ __launch_bounds__(256, 1) void k_rnn(
    const unsigned short* __restrict__ wf, const float* __restrict__ lb,
    unsigned short* ownring, unsigned short* crossring,
    const unsigned short* __restrict__ xpt,
    int* stepslots, int* xcdslots, int sepAvail)
{
  extern __shared__ unsigned char Wl[];     // 163840
  const int bid = blockIdx.x;
  const int g = bid & 7;
  if (g >= 6) return;
  const int l = g >> 1, mg = g & 1;
  const int n = bid >> 3;
  const int tid = threadIdx.x;
  const int lane = tid & 63;
  const int wv = tid >> 6;
  const int l5 = lane >> 5, l31 = lane & 31;
  const int tilebase = (mg*4 + wv) << 5;                 // tile row for this wave
  unsigned char* actb = Wl + 131072 + (wv << 13);        // 8 KB per wave
  unsigned short* hst = (unsigned short*)actb;           // aliased post-GEMM

  // ---- preload W slice (Jb = 2n, 2n+1) into LDS ----
  {
    const us8* src = (const us8*)(wf + ((long)(l*64 + n*2))*4096*8);
    us8* dst = (us8*)Wl;
    for (int i = tid; i < 8192; i += 256) dst[i] = src[i];
  }
  // ---- bias acc-init (D frag: j'_local = (r&3)+8*(r>>2)+4*l5; verified) ----
  f32x16 bias0, bias1;
  #pragma unroll
  for (int r = 0; r < 16; ++r){
    int hc0 = (n*2 + 0)*8 + 2*(r>>2) + l5;
    int hc1 = (n*2 + 1)*8 + 2*(r>>2) + l5;
    bias0[r] = lb[l*G4 + (r&3)*512 + hc0];
    bias1[r] = lb[l*G4 + (r&3)*512 + hc1];
  }
  float cs0[4] = {0.f,0.f,0.f,0.f}, cs1[4] = {0.f,0.f,0.f,0.f};
  __syncthreads();

  // ---- XCD rendezvous (r10-proven): cached own-ring stores only if all 32 WGs
  //      of this (l,mg) group share one XCD; else volatile-only (G16-safe). ----
  unsigned myxcd = 0;
  asm volatile("s_getreg_b32 %0, hwreg(HW_REG_XCC_ID)" : "=s"(myxcd));
  if (tid == 0)
    __hip_atomic_store(xcdslots + g*32 + n, 1 + (int)myxcd,
                       __ATOMIC_RELAXED, __HIP_MEMORY_SCOPE_AGENT);
  int uni;
  {
    int guard = 0, s = 0;
    for (;;){
      s = __hip_atomic_load((const int*)(xcdslots + g*32 + (lane & 31)),
                            __ATOMIC_RELAXED, __HIP_MEMORY_SCOPE_AGENT);
      if (__all(s >= 1) || guard++ > (1 << 17)) break;
      __builtin_amdgcn_s_sleep(2);
    }
    uni = __all(s == 1 + (int)myxcd);
    asm volatile("" ::: "memory");
  }
  const int ownSep = (sepAvail && uni) ? 1 : 0;
  const unsigned short* ownr = ownSep ? ownring : crossring;

  const int* sOwn  = stepslots + g*32;
  const int* sPrev = stepslots + (g - 2)*32;
  int* mySlot = stepslots + g*32 + n;

  for (int t = 0; t < T_; ++t){
    f32x16 a0 = bias0, a1 = bias1;

    if (l == 0){
      // xp left half first (no deps) -> own-wait hides under it
      {
        const unsigned short* gsrc = xpt + (long)t*SLAB + ((long)tilebase << 9)
                                   + lane*8;
        const int SB = 0;
        GEMM_HALF(0)
      }
      if (t > 0){
        wave_wait(sOwn, t);
        const unsigned short* gsrc = ownr + ((long)(t-1)*3 + l)*SLAB
                                   + ((long)tilebase << 9) + lane*8;
        const int SB = 32;
        GEMM_HALF(0)
      }
    } else {
      if (t > 0){
        wave_wait(sOwn, t);
        const unsigned short* gsrc = ownr + ((long)(t-1)*3 + l)*SLAB
                                   + ((long)tilebase << 9) + lane*8;
        const int SB = 32;
        GEMM_HALF(0)
      }
      wave_wait(sPrev, t + 1);
      {
        const unsigned short* gsrc = crossring + ((long)t*3 + (l-1))*SLAB
                                   + ((long)tilebase << 9) + lane*8;
        const int SB = 0;
        GEMM_HALF(1)   // cross stores raw h; consumer applies relu
      }
    }

    // ---- LSTM cell (regs) -> per-wave LDS stage -> ONE coalesced 1 KB store ----
    CELL1(a0, 0)
    CELL1(a1, 1)
    asm volatile("s_waitcnt lgkmcnt(0)" ::: "memory");
    __builtin_amdgcn_sched_barrier(0);
    {
      us8 v = *(const us8*)(hst + l31*24 + l5*8);
      long off = ((long)t*3 + l)*SLAB + ((long)(tilebase + n) << 9) + lane*8;
      if (ownSep) *(us8*)(ownring + off) = v;         // cached -> XCD L2 (dirty)
      *(volatile us8*)(crossring + off) = v;           // write-through -> L3
    }
    __syncthreads();   // drains all 4 waves' stores before publish
    if (tid == 0)
      __hip_atomic_store(mySlot, t + 1, __ATOMIC_RELAXED, __HIP_MEMORY_SCOPE_AGENT);
  }
}

// ================= round-0 fallback (compact) kernels =================

__global__ __launch_bounds__(256) void k_wconv0(const float* __restrict__ w,
                                                unsigned short* __restrict__ wf){
  long d8 = ((long)blockIdx.x*256 + threadIdx.x) * 8;
  int lane = (int)((d8 >> 3) & 63);
  int s    = (int)((d8 >> 9) & 31);
  int J    = (int)((d8 >> 14) & 127);
  int l    = (int)(d8 >> 21);
  int jj = lane & 15, khi = lane >> 4;
  int jp = J*16 + jj;
  int co = (jp & 3)*512 + (jp >> 2);
  int kbase = s*32 + khi*8;
  us8 o;
  #pragma unroll
  for (int e = 0; e < 8; ++e)
    o[e] = f2bf(w[((long)(l*1024 + kbase + e))*2048 + co]);
  *(us8*)(wf + d8) = o;
}

__global__ void k_iout(float* __restrict__ dout, const float* __restrict__ ob){
  int i = blockIdx.x*256 + threadIdx.x;
  if (i < B_*T_*16) dout[i] = ob[i & 15];
}

__global__ __launch_bounds__(256, 2) void k_stage0(
    const float* __restrict__ x, const float* __restrict__ pw, const float* __restrict__ pb,
    const unsigned short* __restrict__ wf, const float* __restrict__ lb,
    const float* __restrict__ ow, float* __restrict__ dout,
    float* __restrict__ cbuf, unsigned short* __restrict__ hb,
    int t, int l)
{
  __shared__ unsigned char Ab[32*2048];
  __shared__ float gsm[32*36];
  __shared__ float xrow[32*16];
  __shared__ float hcell[32*8];

  const int tid = threadIdx.x;
  const int bid = blockIdx.x;
  const int m = bid >> 6;
  const int n = ((bid & 7) << 3) | ((bid >> 3) & 7);
  const int pwr = t & 1, prd = pwr ^ 1;
  const int bg0 = m * 32;

  {
    const unsigned short* src = hb + (((long)prd*3 + l)*256 + bg0)*512;
    for (int i = 0; i < 8; ++i){
      int cid = tid + 256*i;
      int row = cid >> 6, cc = cid & 63;
      us8 v = *(const us8*)(src + (long)row*512 + cc*8);
      *(us8*)(Ab + ((row*2048 + 1024 + cc*16) ^ ((row & 7) << 4))) = v;
    }
  }
  if (l > 0){
    const unsigned short* src = hb + (((long)pwr*3 + (l-1))*256 + bg0)*512;
    for (int i = 0; i < 8; ++i){
      int cid = tid + 256*i;
      int row = cid >> 6, cc = cid & 63;
      us8 v = *(const us8*)(src + (long)row*512 + cc*8);
      #pragma unroll
      for (int e = 0; e < 8; ++e) v[e] = (v[e] & 0x8000u) ? (unsigned short)0 : v[e];
      *(us8*)(Ab + ((row*2048 + cc*16) ^ ((row & 7) << 4))) = v;
    }
  } else {
    {
      int e2 = tid*2;
      int br = e2 >> 4, f = e2 & 15;
      const float* xr = x + ((long)(bg0 + br)*T_ + t)*FIN;
      xrow[e2] = xr[f]; xrow[e2+1] = xr[f+1];
    }
    __syncthreads();
    for (int i = 0; i < 8; ++i){
      int cid = tid + 256*i;
      int row = cid >> 6, cc = cid & 63;
      int c0 = cc*8;
      us8 vv;
      #pragma unroll
      for (int j = 0; j < 8; ++j){
        float a = pb[c0 + j];
        #pragma unroll
        for (int f = 0; f < FIN; ++f) a += xrow[row*16 + f] * pw[f*H_ + c0 + j];
        vv[j] = f2bf(fmaxf(a, 0.f));
      }
      *(us8*)(Ab + ((row*2048 + cc*16) ^ ((row & 7) << 4))) = vv;
    }
  }
  __syncthreads();

  const int lane = tid & 63, wid = tid >> 6;
  const int wm = wid >> 1, wn = wid & 1;
  const int J = n*2 + wn;
  const int arow = wm*16 + (lane & 15);
  const unsigned abase = (unsigned)arow*2048 + ((lane >> 4) << 4);
  const unsigned axor = (unsigned)((arow & 7) << 4);
  const unsigned short* bp = wf + ((((long)l*128 + J)*32)*64 + lane)*8;

  typedef __attribute__((ext_vector_type(4))) float f32x4;
  f32x4 acc = {0.f, 0.f, 0.f, 0.f};
  #pragma unroll
  for (int s = 0; s < 32; ++s){
    bf16x8 af = *(const bf16x8*)(Ab + ((abase + s*64) ^ axor));
    bf16x8 bfr = *(const bf16x8*)(bp + (long)s*512);
    acc = __builtin_amdgcn_mfma_f32_16x16x32_bf16(af, bfr, acc, 0, 0, 0);
  }
  {
    int colb = wn*16 + (lane & 15);
    int rowb = wm*16 + ((lane >> 4) << 2);
    #pragma unroll
    for (int r = 0; r < 4; ++r) gsm[(rowb + r)*36 + colb] = acc[r];
  }
  __syncthreads();

  {
    int bl = tid >> 3, hc = tid & 7;
    float4 g4 = *(float4*)(&gsm[bl*36 + hc*4]);
    int hcol = n*8 + hc;
    int bgl = bg0 + bl;
    float iv = g4.x + lb[l*G4 + hcol];
    float gv = g4.y + lb[l*G4 + 512 + hcol];
    float fv = g4.z + lb[l*G4 + 1024 + hcol];
    float ov = g4.w + lb[l*G4 + 1536 + hcol];
    long coff = ((long)l*256 + bgl)*512 + hcol;
    float cp = cbuf[coff];
    float cn = sigm(fv + 1.f)*cp + sigm(iv)*tanh_(gv);
    float hn = sigm(ov)*tanh_(cn);
    cbuf[coff] = cn;
    hb[(((long)pwr*3 + l)*256 + bgl)*512 + hcol] = f2bf(hn);
    if (l == 2) hcell[bl*8 + hc] = hn;
  }
  if (l == 2){
    __syncthreads();
    #pragma unroll
    for (int q = 0; q < 2; ++q){
      int oid = tid + 256*q;
      int bl = oid >> 4, o = oid & 15;
      float a = 0.f;
      #pragma unroll
      for (int hc = 0; hc < 8; ++hc) a += hcell[bl*8 + hc] * ow[(n*8 + hc)*16 + o];
      atomicAdd(dout + ((long)(bg0 + bl)*T_ + t)*16 + o, a);
    }
  }
}

// ================= launch =================

extern "C" void kernel_launch(void* const* d_in, const int* in_sizes, int n_in,
                              void* d_out, int out_size, void* d_ws, size_t ws_size,
                              hipStream_t stream)
{
  const float* x  = (const float*)d_in[0];
  const float* pw = (const float*)d_in[1];
  const float* pb = (const float*)d_in[2];
  const float* lw = (const float*)d_in[3];
  const float* lb = (const float*)d_in[4];
  const float* ow = (const float*)d_in[5];
  const float* ob = (const float*)d_in[6];
  float* dout = (float*)d_out;

  const size_t RING = 128ull*3*SLAB*2;                 // 100.66 MB
  char* ws = (char*)d_ws;
  size_t off = 0;
  auto carve = [&](size_t bytes){ char* p = ws + off; off += (bytes + 255) & ~(size_t)255; return p; };

  unsigned short* wf    = (unsigned short*)carve(3ull*64*4096*8*2);   // 12.58 MB
  unsigned short* cross = (unsigned short*)carve(RING);               // 100.66 MB
  unsigned short* xpt   = (unsigned short*)carve(128ull*SLAB*2);      // 33.55 MB
  int*            steps = (int*)carve(1024);
  int*            xcds  = (int*)carve(1024);
  size_t need_mid = off;                                              // ~146.9 MB
  unsigned short* own   = (unsigned short*)carve(RING);               // +100.66 MB
  size_t need_lux = off;                                              // ~247.5 MB

  int mode = (ws_size >= need_lux) ? 2 : (ws_size >= need_mid ? 1 : 0);
  if (mode){
    if (hipFuncSetAttribute((const void*)k_rnn,
                            hipFuncAttributeMaxDynamicSharedMemorySize,
                            163840) != hipSuccess)
      mode = 0;
  }

  if (mode){
    int sepAvail = (mode == 2) ? 1 : 0;
    unsigned short* ownp = sepAvail ? own : cross;
    hipMemsetAsync(steps, 0, 2048, stream);            // steps + xcds adjacent
    k_wconv<<<3072, 256, 0, stream>>>(lw, wf);
    k_xp<<<512, 256, 0, stream>>>(x, pw, pb, xpt);
    k_rnn<<<256, 256, 163840, stream>>>(wf, lb, ownp, cross, xpt,
                                        steps, xcds, sepAvail);
    k_out<<<2048, 256, 0, stream>>>(cross, ow, ob, dout);
  } else {
    // round-0 compact fallback (proven, 2199 us)
    size_t o2 = 0;
    auto carve2 = [&](size_t bytes){ char* p = ws + o2; o2 += (bytes + 255) & ~(size_t)255; return p; };
    unsigned short* wf0   = (unsigned short*)carve2(3ull*1024*2048*2);
    float*          cbuf0 = (float*)carve2(3ull*256*512*4);
    unsigned short* hbuf0 = (unsigned short*)carve2(2ull*3*256*512*2);
    hipMemsetAsync(cbuf0, 0, 3ull*256*512*4 + 2ull*3*256*512*2, stream);
    k_wconv0<<<3072, 256, 0, stream>>>(lw, wf0);
    k_iout<<<2048, 256, 0, stream>>>(dout, ob);
    for (int t = 0; t < T_; ++t)
      for (int l = 0; l < 3; ++l)
        k_stage0<<<512, 256, 0, stream>>>(x, pw, pb, wf0, lb, ow, dout,
                                          cbuf0, hbuf0, t, l);
  }
}

// Round 15
// 1225.452 us; speedup vs baseline: 2.6143x; 1.0894x over previous
//
#include <hip/hip_runtime.h>

// RecurrentEncoder: proj(16->512)+relu, 3-layer LSTM (H=512), out head (512->16).
// B=256, T=128. Round 15: r14 with the ONE-LINE FIX of r13/r14's failure — the
// wr1 (right-half W J1 block) register preload had a units bug: +32768 SHORTS
// (J1 block offset) was written inside the *8 parenthesization, reading 8 blocks
// too far. Everything else identical to r14: persistent 192 WGs, XCD colocation
// + rendezvous, contiguous-1KB DMA staging, own-ring L2 / cross-ring L3, W right
// half in VGPRs (zero W ds_reads), left-half-first, r12-proven per-WG flag sync.

typedef __attribute__((ext_vector_type(8)))  short bf16x8;
typedef __attribute__((ext_vector_type(16))) float f32x16;
typedef __attribute__((ext_vector_type(8)))  unsigned short us8;

#define B_  256
#define T_  128
#define FIN 16
#define H_  512
#define G4  2048
#define SLAB 131072   // shorts per (t,l) slab
#define MF(A,B,C) __builtin_amdgcn_mfma_f32_32x32x16_bf16(A,B,C,0,0,0)

static __device__ __forceinline__ float bf2f(unsigned short u){
  return __uint_as_float(((unsigned)u) << 16);
}
static __device__ __forceinline__ unsigned short f2bf(float f){  // RNE
  unsigned u = __float_as_uint(f);
  u += 0x7fffu + ((u >> 16) & 1u);
  return (unsigned short)(u >> 16);
}
static __device__ __forceinline__ float sigm(float x){ return 1.f/(1.f + __expf(-x)); }
static __device__ __forceinline__ float tanh_(float x){ return 1.f - 2.f/(__expf(2.f*x) + 1.f); }

// Wave-autonomous slot wait (r8-r12 proven): lane i polls slots[i&31].
static __device__ __forceinline__ void wave_wait(const int* slotbase, int v){
  int guard = 0;
  for (;;){
    int s = __hip_atomic_load((const int*)(slotbase + (threadIdx.x & 31)),
                              __ATOMIC_RELAXED, __HIP_MEMORY_SCOPE_AGENT);
    if (__all(s >= v) || guard++ > (1 << 17)) break;
    __builtin_amdgcn_s_sleep(2);
  }
  asm volatile("" ::: "memory");
}

// ================= prep kernels (verified) =================

// lstm_w fp32 [3][1024][2048] -> bf16, 32x32x16 A-frag order.
__global__ __launch_bounds__(256) void k_wconv(const float* __restrict__ w,
                                               unsigned short* __restrict__ wfo){
  long idx = (long)blockIdx.x*256 + threadIdx.x;   // 786432
  int lane = (int)(idx & 63);
  int s    = (int)((idx >> 6) & 63);
  int Jb   = (int)((idx >> 12) & 63);
  int l    = (int)(idx >> 18);
  int jp = Jb*32 + (lane & 31);
  int co = (jp & 3)*512 + (jp >> 2);
  int k0 = s*16 + (lane >> 5)*8;
  us8 o;
  #pragma unroll
  for (int e = 0; e < 8; ++e)
    o[e] = f2bf(w[((long)(l*1024 + k0 + e))*2048 + co]);
  *(us8*)(wfo + idx*8) = o;
}

// xp = relu(x @ pw + pb) -> bf16 in TILED layout (r12-verified).
__global__ __launch_bounds__(256) void k_xp(const float* __restrict__ x,
                                            const float* __restrict__ pw,
                                            const float* __restrict__ pb,
                                            unsigned short* __restrict__ xpt){
  __shared__ float sw[FIN*H_];
  __shared__ float sb[H_];
  int tid = threadIdx.x;
  for (int i = tid; i < FIN*H_; i += 256) sw[i] = pw[i];
  for (int i = tid; i < H_;     i += 256) sb[i] = pb[i];
  __syncthreads();
  int r0 = blockIdx.x * 64;
  int c0 = tid * 2;
  int s  = c0 >> 4, kl = c0 & 15;
  for (int rr = 0; rr < 64; ++rr){
    int r = r0 + rr;
    int b = r >> 7, t = r & 127;
    const float* xr = x + (long)r*FIN;
    float a0 = sb[c0], a1 = sb[c0+1];
    #pragma unroll
    for (int f = 0; f < FIN; ++f){
      float xv = xr[f];
      a0 += xv * sw[f*H_ + c0];
      a1 += xv * sw[f*H_ + c0 + 1];
    }
    ushort2 tmp;
    tmp.x = f2bf(fmaxf(a0, 0.f));
    tmp.y = f2bf(fmaxf(a1, 0.f));
    long off = (long)t*SLAB
             + ((((b>>7)*4 + ((b>>5)&3))*32 + s) << 9)
             + ((b&31) + ((kl>>3)<<5))*8 + (kl&7);
    *(ushort2*)(xpt + off) = tmp;
  }
}

// y = h2(tiled slab t,l=2) @ out_w + out_b ; grid 2048 (r12-verified)
__global__ __launch_bounds__(256) void k_out(const unsigned short* __restrict__ ring,
                                             const float* __restrict__ ow,
                                             const float* __restrict__ ob,
                                             float* __restrict__ dout){
  __shared__ float sw[H_*16];
  int tid = threadIdx.x;
  for (int i = tid; i < H_*16; i += 256) sw[i] = ow[i];
  __syncthreads();
  int r0 = blockIdx.x * 16;
  int rr = tid >> 4, o = tid & 15;
  int r = r0 + rr;
  int b = r >> 7, t = r & 127;
  long tb = ((long)t*3 + 2)*SLAB + (((b>>7)*4 + ((b>>5)&3)) << 14);
  float acc = ob[o];
  for (int k8 = 0; k8 < 64; ++k8){
    long off = tb + ((long)(k8 >> 1) << 9) + ((b&31) + ((k8&1)<<5))*8;
    us8 v = *(const us8*)(ring + off);
    #pragma unroll
    for (int e = 0; e < 8; ++e) acc += bf2f(v[e]) * sw[(k8*8 + e)*16 + o];
  }
  dout[(long)r*16 + o] = acc;
}

// ================= persistent RNN kernel =================

// DMA one CONTIGUOUS 1-KB tile.
#define DMA1(I) { \
  __builtin_amdgcn_global_load_lds( \
    (const __attribute__((address_space(1))) void*)(gsrc + (I)*512), \
    (__attribute__((address_space(3))) void*)(actb + (((I) & 7) << 10)), 16, 0, 0); }

#define ISSUE4(G) { DMA1((G)*4+0) DMA1((G)*4+1) DMA1((G)*4+2) DMA1((G)*4+3) }

#define WVM(N) { asm volatile("s_waitcnt vmcnt(" #N ")" ::: "memory"); \
                 __builtin_amdgcn_sched_barrier(0); }
#define LGK0   { asm volatile("s_waitcnt lgkmcnt(0)" ::: "memory"); \
                 __builtin_amdgcn_sched_barrier(0); }

// Left half: W from LDS (s=0..31), optional relu on act.
#define CONS(I, RELU) { \
  bf16x8 w0 = *(const bf16x8*)(Wl + (((I)*64 + lane) << 4)); \
  bf16x8 w1 = *(const bf16x8*)(Wl + (65536 + (((I)*64 + lane) << 4))); \
  bf16x8 b  = *(const bf16x8*)(actb + (((I) & 7) << 10) + (lane << 4)); \
  if (RELU){ _Pragma("unroll") for (int e = 0; e < 8; ++e) if (b[e] < 0) b[e] = 0; } \
  a0 = MF(w0, b, a0); a1 = MF(w1, b, a1); }

// Right half: W from REGISTERS (compile-time index) — zero W ds_reads.
#define CONSR(I) { \
  bf16x8 b = *(const bf16x8*)(actb + (((I) & 7) << 10) + (lane << 4)); \
  a0 = MF(wr0[I], b, a0); a1 = MF(wr1[I], b, a1); }

#define CONS4(G, R)  { CONS((G)*4+0,R) CONS((G)*4+1,R) CONS((G)*4+2,R) CONS((G)*4+3,R) }
#define CONSR4(G)    { CONSR((G)*4+0) CONSR((G)*4+1) CONSR((G)*4+2) CONSR((G)*4+3) }

#define GEMM_HALF_L(R) { \
  ISSUE4(0) ISSUE4(1) \
  WVM(4) CONS4(0,R) LGK0 ISSUE4(2) \
  WVM(4) CONS4(1,R) LGK0 ISSUE4(3) \
  WVM(4) CONS4(2,R) LGK0 ISSUE4(4) \
  WVM(4) CONS4(3,R) LGK0 ISSUE4(5) \
  WVM(4) CONS4(4,R) LGK0 ISSUE4(6) \
  WVM(4) CONS4(5,R) LGK0 ISSUE4(7) \
  WVM(4) CONS4(6,R) \
  WVM(0) CONS4(7,R) }

#define GEMM_HALF_R { \
  ISSUE4(0) ISSUE4(1) \
  WVM(4) CONSR4(0) LGK0 ISSUE4(2) \
  WVM(4) CONSR4(1) LGK0 ISSUE4(3) \
  WVM(4) CONSR4(2) LGK0 ISSUE4(4) \
  WVM(4) CONSR4(3) LGK0 ISSUE4(5) \
  WVM(4) CONSR4(4) LGK0 ISSUE4(6) \
  WVM(4) CONSR4(5) LGK0 ISSUE4(7) \
  WVM(4) CONSR4(6) \
  WVM(0) CONSR4(7) }

// hstage: [32 rows][stride 24 shorts].
#define CELL1(A, JB) { _Pragma("unroll") \
  for (int q = 0; q < 4; ++q){ \
    float iv = A[4*q+0], gv = A[4*q+1], fv = A[4*q+2], ov = A[4*q+3]; \
    float cp = cs##JB[q]; \
    float cn = sigm(fv + 1.f)*cp + sigm(iv)*tanh_(gv); \
    float hn = sigm(ov)*tanh_(cn); \
    cs##JB[q] = cn; \
    hst[l31*24 + JB*8 + 2*q + l5] = f2bf(hn); } }

// grid 256, active 192: g = bid&7 (<6), l = g>>1, mg = g&1, n = bid>>3.
// block 256 = 4 waves, wave wv -> 32 rows. LDS = 160 KiB: W 128 KB + 4x8 KB act.
__global__ __launch_bounds__(256, 1) void k_rnn(
    const unsigned short* __restrict__ wf, const float* __restrict__ lb,
    unsigned short* ownring, unsigned short* crossring,
    const unsigned short* __restrict__ xpt,
    int* stepslots, int* xcdslots, int sepAvail)
{
  extern __shared__ unsigned char Wl[];     // 163840
  const int bid = blockIdx.x;
  const int g = bid & 7;
  if (g >= 6) return;
  const int l = g >> 1, mg = g & 1;
  const int n = bid >> 3;
  const int tid = threadIdx.x;
  const int lane = tid & 63;
  const int wv = tid >> 6;
  const int l5 = lane >> 5, l31 = lane & 31;
  const int tilebase = (mg*4 + wv) << 5;                 // tile row for this wave
  unsigned char* actb = Wl + 131072 + (wv << 13);        // 8 KB per wave
  unsigned short* hst = (unsigned short*)actb;           // aliased post-GEMM

  const unsigned short* wbase = wf + ((long)(l*64 + n*2))*4096*8;

  // ---- preload W into LDS (full slice; left half consumed from LDS) ----
  {
    const us8* src = (const us8*)wbase;
    us8* dst = (us8*)Wl;
    for (int i = tid; i < 8192; i += 256) dst[i] = src[i];
  }
  // ---- preload RIGHT-half W (s=32..63, both J) into REGISTERS ----
  // J1 block starts at +32768 SHORTS (64 KB) — offset OUTSIDE the *8 (r13/r14 bug).
  bf16x8 wr0[32], wr1[32];
  #pragma unroll
  for (int i = 0; i < 32; ++i){
    wr0[i] = *(const bf16x8*)(wbase + ((long)((32+i)*64 + lane))*8);
    wr1[i] = *(const bf16x8*)(wbase + 32768 + ((long)((32+i)*64 + lane))*8);
  }
  // ---- bias acc-init (D frag: j'_local = (r&3)+8*(r>>2)+4*l5; verified) ----
  f32x16 bias0, bias1;
  #pragma unroll
  for (int r = 0; r < 16; ++r){
    int hc0 = (n*2 + 0)*8 + 2*(r>>2) + l5;
    int hc1 = (n*2 + 1)*8 + 2*(r>>2) + l5;
    bias0[r] = lb[l*G4 + (r&3)*512 + hc0];
    bias1[r] = lb[l*G4 + (r&3)*512 + hc1];
  }
  float cs0[4] = {0.f,0.f,0.f,0.f}, cs1[4] = {0.f,0.f,0.f,0.f};
  __syncthreads();

  // ---- XCD rendezvous (r10-proven; G16-safe fallback) ----
  unsigned myxcd = 0;
  asm volatile("s_getreg_b32 %0, hwreg(HW_REG_XCC_ID)" : "=s"(myxcd));
  if (tid == 0)
    __hip_atomic_store(xcdslots + g*32 + n, 1 + (int)myxcd,
                       __ATOMIC_RELAXED, __HIP_MEMORY_SCOPE_AGENT);
  int uni;
  {
    int guard = 0, s = 0;
    for (;;){
      s = __hip_atomic_load((const int*)(xcdslots + g*32 + (lane & 31)),
                            __ATOMIC_RELAXED, __HIP_MEMORY_SCOPE_AGENT);
      if (__all(s >= 1) || guard++ > (1 << 17)) break;
      __builtin_amdgcn_s_sleep(2);
    }
    uni = __all(s == 1 + (int)myxcd);
    asm volatile("" ::: "memory");
  }
  const int ownSep = (sepAvail && uni) ? 1 : 0;
  const unsigned short* ownr = ownSep ? ownring : crossring;

  // ---- per-WG flags (r12-proven): [g][n] ----
  const int* sOwn  = stepslots + g*32;
  const int* sPrev = stepslots + (g - 2)*32;
  int* myFlag = stepslots + g*32 + n;

  for (int t = 0; t < T_; ++t){
    f32x16 a0 = bias0, a1 = bias1;

    // ---- LEFT half first (own-publish latency hides under this for l>0) ----
    if (l == 0){
      const unsigned short* gsrc = xpt + (long)t*SLAB + ((long)tilebase << 9)
                                 + lane*8;
      GEMM_HALF_L(0)
    } else {
      wave_wait(sPrev, t + 1);
      const unsigned short* gsrc = crossring + ((long)t*3 + (l-1))*SLAB
                                 + ((long)tilebase << 9) + lane*8;
      GEMM_HALF_L(1)     // cross stores raw h; consumer applies relu
    }
    // ---- RIGHT half: own h[t-1], W in registers (zero W ds_reads) ----
    if (t > 0){
      wave_wait(sOwn, t);
      const unsigned short* gsrc = ownr + ((long)(t-1)*3 + l)*SLAB
                                 + ((long)tilebase << 9) + lane*8;
      GEMM_HALF_R
    }

    // ---- LSTM cell (regs) -> per-wave LDS stage -> ONE coalesced 1 KB store ----
    CELL1(a0, 0)
    CELL1(a1, 1)
    asm volatile("s_waitcnt lgkmcnt(0)" ::: "memory");
    __builtin_amdgcn_sched_barrier(0);
    {
      us8 v = *(const us8*)(hst + l31*24 + l5*8);
      long off = ((long)t*3 + l)*SLAB + ((long)(tilebase + n) << 9) + lane*8;
      if (ownSep) *(us8*)(ownring + off) = v;         // cached -> XCD L2 (dirty)
      *(volatile us8*)(crossring + off) = v;           // write-through -> L3
    }
    __syncthreads();   // full drain (all 4 waves' stores + LDS) before publish
    if (tid == 0)
      __hip_atomic_store(myFlag, t + 1, __ATOMIC_RELAXED, __HIP_MEMORY_SCOPE_AGENT);
  }
}

// ================= round-0 fallback (compact) kernels =================

__global__ __launch_bounds__(256) void k_wconv0(const float* __restrict__ w,
                                                unsigned short* __restrict__ wf){
  long d8 = ((long)blockIdx.x*256 + threadIdx.x) * 8;
  int lane = (int)((d8 >> 3) & 63);
  int s    = (int)((d8 >> 9) & 31);
  int J    = (int)((d8 >> 14) & 127);
  int l    = (int)(d8 >> 21);
  int jj = lane & 15, khi = lane >> 4;
  int jp = J*16 + jj;
  int co = (jp & 3)*512 + (jp >> 2);
  int kbase = s*32 + khi*8;
  us8 o;
  #pragma unroll
  for (int e = 0; e < 8; ++e)
    o[e] = f2bf(w[((long)(l*1024 + kbase + e))*2048 + co]);
  *(us8*)(wf + d8) = o;
}

__global__ void k_iout(float* __restrict__ dout, const float* __restrict__ ob){
  int i = blockIdx.x*256 + threadIdx.x;
  if (i < B_*T_*16) dout[i] = ob[i & 15];
}

__global__ __launch_bounds__(256, 2) void k_stage0(
    const float* __restrict__ x, const float* __restrict__ pw, const float* __restrict__ pb,
    const unsigned short* __restrict__ wf, const float* __restrict__ lb,
    const float* __restrict__ ow, float* __restrict__ dout,
    float* __restrict__ cbuf, unsigned short* __restrict__ hb,
    int t, int l)
{
  __shared__ unsigned char Ab[32*2048];
  __shared__ float gsm[32*36];
  __shared__ float xrow[32*16];
  __shared__ float hcell[32*8];

  const int tid = threadIdx.x;
  const int bid = blockIdx.x;
  const int m = bid >> 6;
  const int n = ((bid & 7) << 3) | ((bid >> 3) & 7);
  const int pwr = t & 1, prd = pwr ^ 1;
  const int bg0 = m * 32;

  {
    const unsigned short* src = hb + (((long)prd*3 + l)*256 + bg0)*512;
    for (int i = 0; i < 8; ++i){
      int cid = tid + 256*i;
      int row = cid >> 6, cc = cid & 63;
      us8 v = *(const us8*)(src + (long)row*512 + cc*8);
      *(us8*)(Ab + ((row*2048 + 1024 + cc*16) ^ ((row & 7) << 4))) = v;
    }
  }
  if (l > 0){
    const unsigned short* src = hb + (((long)pwr*3 + (l-1))*256 + bg0)*512;
    for (int i = 0; i < 8; ++i){
      int cid = tid + 256*i;
      int row = cid >> 6, cc = cid & 63;
      us8 v = *(const us8*)(src + (long)row*512 + cc*8);
      #pragma unroll
      for (int e = 0; e < 8; ++e) v[e] = (v[e] & 0x8000u) ? (unsigned short)0 : v[e];
      *(us8*)(Ab + ((row*2048 + cc*16) ^ ((row & 7) << 4))) = v;
    }
  } else {
    {
      int e2 = tid*2;
      int br = e2 >> 4, f = e2 & 15;
      const float* xr = x + ((long)(bg0 + br)*T_ + t)*FIN;
      xrow[e2] = xr[f]; xrow[e2+1] = xr[f+1];
    }
    __syncthreads();
    for (int i = 0; i < 8; ++i){
      int cid = tid + 256*i;
      int row = cid >> 6, cc = cid & 63;
      int c0 = cc*8;
      us8 vv;
      #pragma unroll
      for (int j = 0; j < 8; ++j){
        float a = pb[c0 + j];
        #pragma unroll
        for (int f = 0; f < FIN; ++f) a += xrow[row*16 + f] * pw[f*H_ + c0 + j];
        vv[j] = f2bf(fmaxf(a, 0.f));
      }
      *(us8*)(Ab + ((row*2048 + cc*16) ^ ((row & 7) << 4))) = vv;
    }
  }
  __syncthreads();

  const int lane = tid & 63, wid = tid >> 6;
  const int wm = wid >> 1, wn = wid & 1;
  const int J = n*2 + wn;
  const int arow = wm*16 + (lane & 15);
  const unsigned abase = (unsigned)arow*2048 + ((lane >> 4) << 4);
  const unsigned axor = (unsigned)((arow & 7) << 4);
  const unsigned short* bp = wf + ((((long)l*128 + J)*32)*64 + lane)*8;

  typedef __attribute__((ext_vector_type(4))) float f32x4;
  f32x4 acc = {0.f, 0.f, 0.f, 0.f};
  #pragma unroll
  for (int s = 0; s < 32; ++s){
    bf16x8 af = *(const bf16x8*)(Ab + ((abase + s*64) ^ axor));
    bf16x8 bfr = *(const bf16x8*)(bp + (long)s*512);
    acc = __builtin_amdgcn_mfma_f32_16x16x32_bf16(af, bfr, acc, 0, 0, 0);
  }
  {
    int colb = wn*16 + (lane & 15);
    int rowb = wm*16 + ((lane >> 4) << 2);
    #pragma unroll
    for (int r = 0; r < 4; ++r) gsm[(rowb + r)*36 + colb] = acc[r];
  }
  __syncthreads();

  {
    int bl = tid >> 3, hc = tid & 7;
    float4 g4 = *(float4*)(&gsm[bl*36 + hc*4]);
    int hcol = n*8 + hc;
    int bgl = bg0 + bl;
    float iv = g4.x + lb[l*G4 + hcol];
    float gv = g4.y + lb[l*G4 + 512 + hcol];
    float fv = g4.z + lb[l*G4 + 1024 + hcol];
    float ov = g4.w + lb[l*G4 + 1536 + hcol];
    long coff = ((long)l*256 + bgl)*512 + hcol;
    float cp = cbuf[coff];
    float cn = sigm(fv + 1.f)*cp + sigm(iv)*tanh_(gv);
    float hn = sigm(ov)*tanh_(cn);
    cbuf[coff] = cn;
    hb[(((long)pwr*3 + l)*256 + bgl)*512 + hcol] = f2bf(hn);
    if (l == 2) hcell[bl*8 + hc] = hn;
  }
  if (l == 2){
    __syncthreads();
    #pragma unroll
    for (int q = 0; q < 2; ++q){
      int oid = tid + 256*q;
      int bl = oid >> 4, o = oid & 15;
      float a = 0.f;
      #pragma unroll
      for (int hc = 0; hc < 8; ++hc) a += hcell[bl*8 + hc] * ow[(n*8 + hc)*16 + o];
      atomicAdd(dout + ((long)(bg0 + bl)*T_ + t)*16 + o, a);
    }
  }
}

// ================= launch =================

extern "C" void kernel_launch(void* const* d_in, const int* in_sizes, int n_in,
                              void* d_out, int out_size, void* d_ws, size_t ws_size,
                              hipStream_t stream)
{
  const float* x  = (const float*)d_in[0];
  const float* pw = (const float*)d_in[1];
  const float* pb = (const float*)d_in[2];
  const float* lw = (const float*)d_in[3];
  const float* lb = (const float*)d_in[4];
  const float* ow = (const float*)d_in[5];
  const float* ob = (const float*)d_in[6];
  float* dout = (float*)d_out;

  const size_t RING = 128ull*3*SLAB*2;                 // 100.66 MB
  char* ws = (char*)d_ws;
  size_t off = 0;
  auto carve = [&](size_t bytes){ char* p = ws + off; off += (bytes + 255) & ~(size_t)255; return p; };

  unsigned short* wf    = (unsigned short*)carve(3ull*64*4096*8*2);   // 12.58 MB
  unsigned short* cross = (unsigned short*)carve(RING);               // 100.66 MB
  unsigned short* xpt   = (unsigned short*)carve(128ull*SLAB*2);      // 33.55 MB
  int*            steps = (int*)carve(1024);                          // [6][32]
  int*            xcds  = (int*)carve(1024);
  size_t need_mid = off;                                              // ~146.9 MB
  unsigned short* own   = (unsigned short*)carve(RING);               // +100.66 MB
  size_t need_lux = off;                                              // ~247.5 MB

  int mode = (ws_size >= need_lux) ? 2 : (ws_size >= need_mid ? 1 : 0);
  if (mode){
    if (hipFuncSetAttribute((const void*)k_rnn,
                            hipFuncAttributeMaxDynamicSharedMemorySize,
                            163840) != hipSuccess)
      mode = 0;
  }

  if (mode){
    int sepAvail = (mode == 2) ? 1 : 0;
    unsigned short* ownp = sepAvail ? own : cross;
    hipMemsetAsync(steps, 0, 2048, stream);            // steps + xcds adjacent
    k_wconv<<<3072, 256, 0, stream>>>(lw, wf);
    k_xp<<<512, 256, 0, stream>>>(x, pw, pb, xpt);
    k_rnn<<<256, 256, 163840, stream>>>(wf, lb, ownp, cross, xpt,
                                        steps, xcds, sepAvail);
    k_out<<<2048, 256, 0, stream>>>(cross, ow, ob, dout);
  } else {
    // round-0 compact fallback (proven, 2199 us)
    size_t o2 = 0;
    auto carve2 = [&](size_t bytes){ char* p = ws + o2; o2 += (bytes + 255) & ~(size_t)255; return p; };
    unsigned short* wf0   = (unsigned short*)carve2(3ull*1024*2048*2);
    float*          cbuf0 = (float*)carve2(3ull*256*512*4);
    unsigned short* hbuf0 = (unsigned short*)carve2(2ull*3*256*512*2);
    hipMemsetAsync(cbuf0, 0, 3ull*256*512*4 + 2ull*3*256*512*2, stream);
    k_wconv0<<<3072, 256, 0, stream>>>(lw, wf0);
    k_iout<<<2048, 256, 0, stream>>>(dout, ob);
    for (int t = 0; t < T_; ++t)
      for (int l = 0; l < 3; ++l)
        k_stage0<<<512, 256, 0, stream>>>(x, pw, pb, wf0, lb, ow, dout,
                                          cbuf0, hbuf0, t, l);
  }
}

// Round 16
// 1181.016 us; speedup vs baseline: 2.7127x; 1.0376x over previous
//
#include <hip/hip_runtime.h>

// RecurrentEncoder: proj(16->512)+relu, 3-layer LSTM (H=512), out head (512->16).
// B=256, T=128. Round 16: r15 (PASS, 1225us) + LDS re-plan: W-in-LDS shrunk to
// the LEFT half only (64 KB; right half is in VGPRs since r15) -> act staging
// grows 8->24 KB/wave (24 slots), DMA pipeline depth 2->5 groups (latency fully
// covered: stall ~ L2/L3_latency - 4*consume ~ 0). Trailing LGK0 added to GEMM
// macros (explicit LDS write-after-read guard at half/CELL boundaries).
// All else r15-proven: 192 WGs (l,mg,n), XCD colocation + rendezvous, own-ring
// L2 / cross-ring L3, per-WG flags + __syncthreads publish, 32x32x16 MFMA.

typedef __attribute__((ext_vector_type(8)))  short bf16x8;
typedef __attribute__((ext_vector_type(16))) float f32x16;
typedef __attribute__((ext_vector_type(8)))  unsigned short us8;

#define B_  256
#define T_  128
#define FIN 16
#define H_  512
#define G4  2048
#define SLAB 131072   // shorts per (t,l) slab
#define MF(A,B,C) __builtin_amdgcn_mfma_f32_32x32x16_bf16(A,B,C,0,0,0)

static __device__ __forceinline__ float bf2f(unsigned short u){
  return __uint_as_float(((unsigned)u) << 16);
}
static __device__ __forceinline__ unsigned short f2bf(float f){  // RNE
  unsigned u = __float_as_uint(f);
  u += 0x7fffu + ((u >> 16) & 1u);
  return (unsigned short)(u >> 16);
}
static __device__ __forceinline__ float sigm(float x){ return 1.f/(1.f + __expf(-x)); }
static __device__ __forceinline__ float tanh_(float x){ return 1.f - 2.f/(__expf(2.f*x) + 1.f); }

// Wave-autonomous slot wait (r8-r15 proven): lane i polls slots[i&31].
static __device__ __forceinline__ void wave_wait(const int* slotbase, int v){
  int guard = 0;
  for (;;){
    int s = __hip_atomic_load((const int*)(slotbase + (threadIdx.x & 31)),
                              __ATOMIC_RELAXED, __HIP_MEMORY_SCOPE_AGENT);
    if (__all(s >= v) || guard++ > (1 << 17)) break;
    __builtin_amdgcn_s_sleep(2);
  }
  asm volatile("" ::: "memory");
}

// ================= prep kernels (verified) =================

// lstm_w fp32 [3][1024][2048] -> bf16, 32x32x16 A-frag order.
__global__ __launch_bounds__(256) void k_wconv(const float* __restrict__ w,
                                               unsigned short* __restrict__ wfo){
  long idx = (long)blockIdx.x*256 + threadIdx.x;   // 786432
  int lane = (int)(idx & 63);
  int s    = (int)((idx >> 6) & 63);
  int Jb   = (int)((idx >> 12) & 63);
  int l    = (int)(idx >> 18);
  int jp = Jb*32 + (lane & 31);
  int co = (jp & 3)*512 + (jp >> 2);
  int k0 = s*16 + (lane >> 5)*8;
  us8 o;
  #pragma unroll
  for (int e = 0; e < 8; ++e)
    o[e] = f2bf(w[((long)(l*1024 + k0 + e))*2048 + co]);
  *(us8*)(wfo + idx*8) = o;
}

// xp = relu(x @ pw + pb) -> bf16 in TILED layout (r12-verified).
__global__ __launch_bounds__(256) void k_xp(const float* __restrict__ x,
                                            const float* __restrict__ pw,
                                            const float* __restrict__ pb,
                                            unsigned short* __restrict__ xpt){
  __shared__ float sw[FIN*H_];
  __shared__ float sb[H_];
  int tid = threadIdx.x;
  for (int i = tid; i < FIN*H_; i += 256) sw[i] = pw[i];
  for (int i = tid; i < H_;     i += 256) sb[i] = pb[i];
  __syncthreads();
  int r0 = blockIdx.x * 64;
  int c0 = tid * 2;
  int s  = c0 >> 4, kl = c0 & 15;
  for (int rr = 0; rr < 64; ++rr){
    int r = r0 + rr;
    int b = r >> 7, t = r & 127;
    const float* xr = x + (long)r*FIN;
    float a0 = sb[c0], a1 = sb[c0+1];
    #pragma unroll
    for (int f = 0; f < FIN; ++f){
      float xv = xr[f];
      a0 += xv * sw[f*H_ + c0];
      a1 += xv * sw[f*H_ + c0 + 1];
    }
    ushort2 tmp;
    tmp.x = f2bf(fmaxf(a0, 0.f));
    tmp.y = f2bf(fmaxf(a1, 0.f));
    long off = (long)t*SLAB
             + ((((b>>7)*4 + ((b>>5)&3))*32 + s) << 9)
             + ((b&31) + ((kl>>3)<<5))*8 + (kl&7);
    *(ushort2*)(xpt + off) = tmp;
  }
}

// y = h2(tiled slab t,l=2) @ out_w + out_b ; grid 2048 (r12-verified)
__global__ __launch_bounds__(256) void k_out(const unsigned short* __restrict__ ring,
                                             const float* __restrict__ ow,
                                             const float* __restrict__ ob,
                                             float* __restrict__ dout){
  __shared__ float sw[H_*16];
  int tid = threadIdx.x;
  for (int i = tid; i < H_*16; i += 256) sw[i] = ow[i];
  __syncthreads();
  int r0 = blockIdx.x * 16;
  int rr = tid >> 4, o = tid & 15;
  int r = r0 + rr;
  int b = r >> 7, t = r & 127;
  long tb = ((long)t*3 + 2)*SLAB + (((b>>7)*4 + ((b>>5)&3)) << 14);
  float acc = ob[o];
  for (int k8 = 0; k8 < 64; ++k8){
    long off = tb + ((long)(k8 >> 1) << 9) + ((b&31) + ((k8&1)<<5))*8;
    us8 v = *(const us8*)(ring + off);
    #pragma unroll
    for (int e = 0; e < 8; ++e) acc += bf2f(v[e]) * sw[(k8*8 + e)*16 + o];
  }
  dout[(long)r*16 + o] = acc;
}

// ================= persistent RNN kernel =================

// DMA one CONTIGUOUS 1-KB tile into slot I%24 of this wave's 24-slot buffer.
#define DMA1(I) { \
  __builtin_amdgcn_global_load_lds( \
    (const __attribute__((address_space(1))) void*)(gsrc + (I)*512), \
    (__attribute__((address_space(3))) void*)(actb + (((I) % 24) << 10)), 16, 0, 0); }

#define ISSUE4(G) { DMA1((G)*4+0) DMA1((G)*4+1) DMA1((G)*4+2) DMA1((G)*4+3) }

#define WVM(N) { asm volatile("s_waitcnt vmcnt(" #N ")" ::: "memory"); \
                 __builtin_amdgcn_sched_barrier(0); }
#define LGK0   { asm volatile("s_waitcnt lgkmcnt(0)" ::: "memory"); \
                 __builtin_amdgcn_sched_barrier(0); }

// Left half: W from LDS — J0 block at byte 0, J1 block at byte 32768 (64 KB total).
#define CONS(I, RELU) { \
  bf16x8 w0 = *(const bf16x8*)(Wl + (((I)*64 + lane) << 4)); \
  bf16x8 w1 = *(const bf16x8*)(Wl + (32768 + (((I)*64 + lane) << 4))); \
  bf16x8 b  = *(const bf16x8*)(actb + (((I) % 24) << 10) + (lane << 4)); \
  if (RELU){ _Pragma("unroll") for (int e = 0; e < 8; ++e) if (b[e] < 0) b[e] = 0; } \
  a0 = MF(w0, b, a0); a1 = MF(w1, b, a1); }

// Right half: W from REGISTERS (compile-time index) — zero W ds_reads.
#define CONSR(I) { \
  bf16x8 b = *(const bf16x8*)(actb + (((I) % 24) << 10) + (lane << 4)); \
  a0 = MF(wr0[I], b, a0); a1 = MF(wr1[I], b, a1); }

#define CONS4(G, R)  { CONS((G)*4+0,R) CONS((G)*4+1,R) CONS((G)*4+2,R) CONS((G)*4+3,R) }
#define CONSR4(G)    { CONSR((G)*4+0) CONSR((G)*4+1) CONSR((G)*4+2) CONSR((G)*4+3) }

// Depth-5 pipeline over 8 groups; slot reuse (g+5 vs g-1, 24 slots apart) is
// guarded by the LGK0 drains; trailing LGK0 = write-after-read guard for the
// next half's DMAs / CELL's LDS writes.
#define GEMM5_L(R) { \
  ISSUE4(0) ISSUE4(1) ISSUE4(2) ISSUE4(3) ISSUE4(4) \
  WVM(16) CONS4(0,R) LGK0 ISSUE4(5) \
  WVM(16) CONS4(1,R) LGK0 ISSUE4(6) \
  WVM(16) CONS4(2,R) LGK0 ISSUE4(7) \
  WVM(16) CONS4(3,R) \
  WVM(12) CONS4(4,R) \
  WVM(8)  CONS4(5,R) \
  WVM(4)  CONS4(6,R) \
  WVM(0)  CONS4(7,R) \
  LGK0 }

#define GEMM5_R { \
  ISSUE4(0) ISSUE4(1) ISSUE4(2) ISSUE4(3) ISSUE4(4) \
  WVM(16) CONSR4(0) LGK0 ISSUE4(5) \
  WVM(16) CONSR4(1) LGK0 ISSUE4(6) \
  WVM(16) CONSR4(2) LGK0 ISSUE4(7) \
  WVM(16) CONSR4(3) \
  WVM(12) CONSR4(4) \
  WVM(8)  CONSR4(5) \
  WVM(4)  CONSR4(6) \
  WVM(0)  CONSR4(7) \
  LGK0 }

// hstage: [32 rows][stride 24 shorts].
#define CELL1(A, JB) { _Pragma("unroll") \
  for (int q = 0; q < 4; ++q){ \
    float iv = A[4*q+0], gv = A[4*q+1], fv = A[4*q+2], ov = A[4*q+3]; \
    float cp = cs##JB[q]; \
    float cn = sigm(fv + 1.f)*cp + sigm(iv)*tanh_(gv); \
    float hn = sigm(ov)*tanh_(cn); \
    cs##JB[q] = cn; \
    hst[l31*24 + JB*8 + 2*q + l5] = f2bf(hn); } }

// grid 256, active 192: g = bid&7 (<6), l = g>>1, mg = g&1, n = bid>>3.
// block 256 = 4 waves. LDS = 160 KiB: W-left 64 KB + 4 x 24 KB act staging.
__global__ __launch_bounds__(256, 1) void k_rnn(
    const unsigned short* __restrict__ wf, const float* __restrict__ lb,
    unsigned short* ownring, unsigned short* crossring,
    const unsigned short* __restrict__ xpt,
    int* stepslots, int* xcdslots, int sepAvail)
{
  extern __shared__ unsigned char Wl[];     // 163840
  const int bid = blockIdx.x;
  const int g = bid & 7;
  if (g >= 6) return;
  const int l = g >> 1, mg = g & 1;
  const int n = bid >> 3;
  const int tid = threadIdx.x;
  const int lane = tid & 63;
  const int wv = tid >> 6;
  const int l5 = lane >> 5, l31 = lane & 31;
  const int tilebase = (mg*4 + wv) << 5;                 // tile row for this wave
  unsigned char* actb = Wl + 65536 + wv*24576;           // 24 KB per wave
  unsigned short* hst = (unsigned short*)actb;           // aliased post-GEMM

  const unsigned short* wbase = wf + ((long)(l*64 + n*2))*4096*8;

  // ---- preload LEFT-half W into LDS: J0 s=0..31 -> bytes [0,32K),
  //      J1 s=0..31 -> bytes [32K,64K). Source J1 block at +32768 SHORTS. ----
  {
    us8* dst = (us8*)Wl;
    const us8* sj0 = (const us8*)wbase;
    const us8* sj1 = (const us8*)(wbase + 32768);
    for (int i = tid; i < 4096; i += 256)
      dst[i] = (i < 2048) ? sj0[i] : sj1[i - 2048];
  }
  // ---- preload RIGHT-half W (s=32..63, both J) into REGISTERS ----
  bf16x8 wr0[32], wr1[32];
  #pragma unroll
  for (int i = 0; i < 32; ++i){
    wr0[i] = *(const bf16x8*)(wbase + ((long)((32+i)*64 + lane))*8);
    wr1[i] = *(const bf16x8*)(wbase + 32768 + ((long)((32+i)*64 + lane))*8);
  }
  // ---- bias acc-init (D frag: j'_local = (r&3)+8*(r>>2)+4*l5; verified) ----
  f32x16 bias0, bias1;
  #pragma unroll
  for (int r = 0; r < 16; ++r){
    int hc0 = (n*2 + 0)*8 + 2*(r>>2) + l5;
    int hc1 = (n*2 + 1)*8 + 2*(r>>2) + l5;
    bias0[r] = lb[l*G4 + (r&3)*512 + hc0];
    bias1[r] = lb[l*G4 + (r&3)*512 + hc1];
  }
  float cs0[4] = {0.f,0.f,0.f,0.f}, cs1[4] = {0.f,0.f,0.f,0.f};
  __syncthreads();

  // ---- XCD rendezvous (r10-proven; G16-safe fallback) ----
  unsigned myxcd = 0;
  asm volatile("s_getreg_b32 %0, hwreg(HW_REG_XCC_ID)" : "=s"(myxcd));
  if (tid == 0)
    __hip_atomic_store(xcdslots + g*32 + n, 1 + (int)myxcd,
                       __ATOMIC_RELAXED, __HIP_MEMORY_SCOPE_AGENT);
  int uni;
  {
    int guard = 0, s = 0;
    for (;;){
      s = __hip_atomic_load((const int*)(xcdslots + g*32 + (lane & 31)),
                            __ATOMIC_RELAXED, __HIP_MEMORY_SCOPE_AGENT);
      if (__all(s >= 1) || guard++ > (1 << 17)) break;
      __builtin_amdgcn_s_sleep(2);
    }
    uni = __all(s == 1 + (int)myxcd);
    asm volatile("" ::: "memory");
  }
  const int ownSep = (sepAvail && uni) ? 1 : 0;
  const unsigned short* ownr = ownSep ? ownring : crossring;

  // ---- per-WG flags (r12-proven): [g][n] ----
  const int* sOwn  = stepslots + g*32;
  const int* sPrev = stepslots + (g - 2)*32;
  int* myFlag = stepslots + g*32 + n;

  for (int t = 0; t < T_; ++t){
    f32x16 a0 = bias0, a1 = bias1;

    // ---- LEFT half first (own-publish latency hides under this for l>0) ----
    if (l == 0){
      const unsigned short* gsrc = xpt + (long)t*SLAB + ((long)tilebase << 9)
                                 + lane*8;
      GEMM5_L(0)
    } else {
      wave_wait(sPrev, t + 1);
      const unsigned short* gsrc = crossring + ((long)t*3 + (l-1))*SLAB
                                 + ((long)tilebase << 9) + lane*8;
      GEMM5_L(1)     // cross stores raw h; consumer applies relu
    }
    // ---- RIGHT half: own h[t-1], W in registers (zero W ds_reads) ----
    if (t > 0){
      wave_wait(sOwn, t);
      const unsigned short* gsrc = ownr + ((long)(t-1)*3 + l)*SLAB
                                 + ((long)tilebase << 9) + lane*8;
      GEMM5_R
    }

    // ---- LSTM cell (regs) -> per-wave LDS stage -> ONE coalesced 1 KB store ----
    CELL1(a0, 0)
    CELL1(a1, 1)
    asm volatile("s_waitcnt lgkmcnt(0)" ::: "memory");
    __builtin_amdgcn_sched_barrier(0);
    {
      us8 v = *(const us8*)(hst + l31*24 + l5*8);
      long off = ((long)t*3 + l)*SLAB + ((long)(tilebase + n) << 9) + lane*8;
      if (ownSep) *(us8*)(ownring + off) = v;         // cached -> XCD L2 (dirty)
      *(volatile us8*)(crossring + off) = v;           // write-through -> L3
    }
    __syncthreads();   // full drain (all 4 waves' stores + LDS) before publish
    if (tid == 0)
      __hip_atomic_store(myFlag, t + 1, __ATOMIC_RELAXED, __HIP_MEMORY_SCOPE_AGENT);
  }
}

// ================= round-0 fallback (compact) kernels =================

__global__ __launch_bounds__(256) void k_wconv0(const float* __restrict__ w,
                                                unsigned short* __restrict__ wf){
  long d8 = ((long)blockIdx.x*256 + threadIdx.x) * 8;
  int lane = (int)((d8 >> 3) & 63);
  int s    = (int)((d8 >> 9) & 31);
  int J    = (int)((d8 >> 14) & 127);
  int l    = (int)(d8 >> 21);
  int jj = lane & 15, khi = lane >> 4;
  int jp = J*16 + jj;
  int co = (jp & 3)*512 + (jp >> 2);
  int kbase = s*32 + khi*8;
  us8 o;
  #pragma unroll
  for (int e = 0; e < 8; ++e)
    o[e] = f2bf(w[((long)(l*1024 + kbase + e))*2048 + co]);
  *(us8*)(wf + d8) = o;
}

__global__ void k_iout(float* __restrict__ dout, const float* __restrict__ ob){
  int i = blockIdx.x*256 + threadIdx.x;
  if (i < B_*T_*16) dout[i] = ob[i & 15];
}

__global__ __launch_bounds__(256, 2) void k_stage0(
    const float* __restrict__ x, const float* __restrict__ pw, const float* __restrict__ pb,
    const unsigned short* __restrict__ wf, const float* __restrict__ lb,
    const float* __restrict__ ow, float* __restrict__ dout,
    float* __restrict__ cbuf, unsigned short* __restrict__ hb,
    int t, int l)
{
  __shared__ unsigned char Ab[32*2048];
  __shared__ float gsm[32*36];
  __shared__ float xrow[32*16];
  __shared__ float hcell[32*8];

  const int tid = threadIdx.x;
  const int bid = blockIdx.x;
  const int m = bid >> 6;
  const int n = ((bid & 7) << 3) | ((bid >> 3) & 7);
  const int pwr = t & 1, prd = pwr ^ 1;
  const int bg0 = m * 32;

  {
    const unsigned short* src = hb + (((long)prd*3 + l)*256 + bg0)*512;
    for (int i = 0; i < 8; ++i){
      int cid = tid + 256*i;
      int row = cid >> 6, cc = cid & 63;
      us8 v = *(const us8*)(src + (long)row*512 + cc*8);
      *(us8*)(Ab + ((row*2048 + 1024 + cc*16) ^ ((row & 7) << 4))) = v;
    }
  }
  if (l > 0){
    const unsigned short* src = hb + (((long)pwr*3 + (l-1))*256 + bg0)*512;
    for (int i = 0; i < 8; ++i){
      int cid = tid + 256*i;
      int row = cid >> 6, cc = cid & 63;
      us8 v = *(const us8*)(src + (long)row*512 + cc*8);
      #pragma unroll
      for (int e = 0; e < 8; ++e) v[e] = (v[e] & 0x8000u) ? (unsigned short)0 : v[e];
      *(us8*)(Ab + ((row*2048 + cc*16) ^ ((row & 7) << 4))) = v;
    }
  } else {
    {
      int e2 = tid*2;
      int br = e2 >> 4, f = e2 & 15;
      const float* xr = x + ((long)(bg0 + br)*T_ + t)*FIN;
      xrow[e2] = xr[f]; xrow[e2+1] = xr[f+1];
    }
    __syncthreads();
    for (int i = 0; i < 8; ++i){
      int cid = tid + 256*i;
      int row = cid >> 6, cc = cid & 63;
      int c0 = cc*8;
      us8 vv;
      #pragma unroll
      for (int j = 0; j < 8; ++j){
        float a = pb[c0 + j];
        #pragma unroll
        for (int f = 0; f < FIN; ++f) a += xrow[row*16 + f] * pw[f*H_ + c0 + j];
        vv[j] = f2bf(fmaxf(a, 0.f));
      }
      *(us8*)(Ab + ((row*2048 + cc*16) ^ ((row & 7) << 4))) = vv;
    }
  }
  __syncthreads();

  const int lane = tid & 63, wid = tid >> 6;
  const int wm = wid >> 1, wn = wid & 1;
  const int J = n*2 + wn;
  const int arow = wm*16 + (lane & 15);
  const unsigned abase = (unsigned)arow*2048 + ((lane >> 4) << 4);
  const unsigned axor = (unsigned)((arow & 7) << 4);
  const unsigned short* bp = wf + ((((long)l*128 + J)*32)*64 + lane)*8;

  typedef __attribute__((ext_vector_type(4))) float f32x4;
  f32x4 acc = {0.f, 0.f, 0.f, 0.f};
  #pragma unroll
  for (int s = 0; s < 32; ++s){
    bf16x8 af = *(const bf16x8*)(Ab + ((abase + s*64) ^ axor));
    bf16x8 bfr = *(const bf16x8*)(bp + (long)s*512);
    acc = __builtin_amdgcn_mfma_f32_16x16x32_bf16(af, bfr, acc, 0, 0, 0);
  }
  {
    int colb = wn*16 + (lane & 15);
    int rowb = wm*16 + ((lane >> 4) << 2);
    #pragma unroll
    for (int r = 0; r < 4; ++r) gsm[(rowb + r)*36 + colb] = acc[r];
  }
  __syncthreads();

  {
    int bl = tid >> 3, hc = tid & 7;
    float4 g4 = *(float4*)(&gsm[bl*36 + hc*4]);
    int hcol = n*8 + hc;
    int bgl = bg0 + bl;
    float iv = g4.x + lb[l*G4 + hcol];
    float gv = g4.y + lb[l*G4 + 512 + hcol];
    float fv = g4.z + lb[l*G4 + 1024 + hcol];
    float ov = g4.w + lb[l*G4 + 1536 + hcol];
    long coff = ((long)l*256 + bgl)*512 + hcol;
    float cp = cbuf[coff];
    float cn = sigm(fv + 1.f)*cp + sigm(iv)*tanh_(gv);
    float hn = sigm(ov)*tanh_(cn);
    cbuf[coff] = cn;
    hb[(((long)pwr*3 + l)*256 + bgl)*512 + hcol] = f2bf(hn);
    if (l == 2) hcell[bl*8 + hc] = hn;
  }
  if (l == 2){
    __syncthreads();
    #pragma unroll
    for (int q = 0; q < 2; ++q){
      int oid = tid + 256*q;
      int bl = oid >> 4, o = oid & 15;
      float a = 0.f;
      #pragma unroll
      for (int hc = 0; hc < 8; ++hc) a += hcell[bl*8 + hc] * ow[(n*8 + hc)*16 + o];
      atomicAdd(dout + ((long)(bg0 + bl)*T_ + t)*16 + o, a);
    }
  }
}

// ================= launch =================

extern "C" void kernel_launch(void* const* d_in, const int* in_sizes, int n_in,
                              void* d_out, int out_size, void* d_ws, size_t ws_size,
                              hipStream_t stream)
{
  const float* x  = (const float*)d_in[0];
  const float* pw = (const float*)d_in[1];
  const float* pb = (const float*)d_in[2];
  const float* lw = (const float*)d_in[3];
  const float* lb = (const float*)d_in[4];
  const float* ow = (const float*)d_in[5];
  const float* ob = (const float*)d_in[6];
  float* dout = (float*)d_out;

  const size_t RING = 128ull*3*SLAB*2;                 // 100.66 MB
  char* ws = (char*)d_ws;
  size_t off = 0;
  auto carve = [&](size_t bytes){ char* p = ws + off; off += (bytes + 255) & ~(size_t)255; return p; };

  unsigned short* wf    = (unsigned short*)carve(3ull*64*4096*8*2);   // 12.58 MB
  unsigned short* cross = (unsigned short*)carve(RING);               // 100.66 MB
  unsigned short* xpt   = (unsigned short*)carve(128ull*SLAB*2);      // 33.55 MB
  int*            steps = (int*)carve(1024);                          // [6][32]
  int*            xcds  = (int*)carve(1024);
  size_t need_mid = off;                                              // ~146.9 MB
  unsigned short* own   = (unsigned short*)carve(RING);               // +100.66 MB
  size_t need_lux = off;                                              // ~247.5 MB

  int mode = (ws_size >= need_lux) ? 2 : (ws_size >= need_mid ? 1 : 0);
  if (mode){
    if (hipFuncSetAttribute((const void*)k_rnn,
                            hipFuncAttributeMaxDynamicSharedMemorySize,
                            163840) != hipSuccess)
      mode = 0;
  }

  if (mode){
    int sepAvail = (mode == 2) ? 1 : 0;
    unsigned short* ownp = sepAvail ? own : cross;
    hipMemsetAsync(steps, 0, 2048, stream);            // steps + xcds adjacent
    k_wconv<<<3072, 256, 0, stream>>>(lw, wf);
    k_xp<<<512, 256, 0, stream>>>(x, pw, pb, xpt);
    k_rnn<<<256, 256, 163840, stream>>>(wf, lb, ownp, cross, xpt,
                                        steps, xcds, sepAvail);
    k_out<<<2048, 256, 0, stream>>>(cross, ow, ob, dout);
  } else {
    // round-0 compact fallback (proven, 2199 us)
    size_t o2 = 0;
    auto carve2 = [&](size_t bytes){ char* p = ws + o2; o2 += (bytes + 255) & ~(size_t)255; return p; };
    unsigned short* wf0   = (unsigned short*)carve2(3ull*1024*2048*2);
    float*          cbuf0 = (float*)carve2(3ull*256*512*4);
    unsigned short* hbuf0 = (unsigned short*)carve2(2ull*3*256*512*2);
    hipMemsetAsync(cbuf0, 0, 3ull*256*512*4 + 2ull*3*256*512*2, stream);
    k_wconv0<<<3072, 256, 0, stream>>>(lw, wf0);
    k_iout<<<2048, 256, 0, stream>>>(dout, ob);
    for (int t = 0; t < T_; ++t)
      for (int l = 0; l < 3; ++l)
        k_stage0<<<512, 256, 0, stream>>>(x, pw, pb, wf0, lb, ow, dout,
                                          cbuf0, hbuf0, t, l);
  }
}